// Round 7
// baseline (893.666 us; speedup 1.0000x reference)
//
#include <hip/hip_runtime.h>

#define FEAT 32
#define EMB 32
#define HID 128
#define NGRAPHS 64

typedef short short8 __attribute__((ext_vector_type(8)));
typedef float f32x4 __attribute__((ext_vector_type(4)));

union B8 { uint4 q; unsigned u[4]; short8 v; };

// round-to-nearest-even bf16, returned as f32 bits with low16 zeroed
__device__ __forceinline__ unsigned bf16_rne_bits(float f) {
  unsigned u = __float_as_uint(f);
  unsigned r = u + 0x7FFFu + ((u >> 16) & 1u);
  return r & 0xFFFF0000u;
}
// split a,b (f32) into packed bf16 hi-pair and lo-pair (elem0 low16, elem1 high16)
__device__ __forceinline__ void split2(float a, float b, unsigned& hp, unsigned& lp) {
  unsigned ha = bf16_rne_bits(a), hb = bf16_rne_bits(b);
  float la = a - __uint_as_float(ha), lb = b - __uint_as_float(hb);
  unsigned laa = bf16_rne_bits(la), lbb = bf16_rne_bits(lb);
  hp = (ha >> 16) | (hb & 0xFFFF0000u);
  lp = (laa >> 16) | (lbb & 0xFFFF0000u);
}

// ---------- CSR build ----------
__global__ void hist_k(const int* __restrict__ dst, int* __restrict__ indeg, int E) {
  int e = blockIdx.x * blockDim.x + threadIdx.x;
  if (e < E) atomicAdd(&indeg[dst[e]], 1);
}

__global__ void dinv_k(const int* __restrict__ indeg, float* __restrict__ dinv, int N) {
  int i = blockIdx.x * blockDim.x + threadIdx.x;
  if (i < N) dinv[i] = rsqrtf((float)indeg[i] + 1.0f);  // +1 self loop
}

// ---------- parallel 3-phase exclusive scan of indeg ----------
__global__ __launch_bounds__(1024) void scanA_k(const int* __restrict__ indeg,
                                                int* __restrict__ excl,
                                                int* __restrict__ bsum, int N) {
  __shared__ int wsum[16];
  int i = blockIdx.x * 1024 + threadIdx.x;
  const int lane = threadIdx.x & 63;
  const int wid = threadIdx.x >> 6;
  int val = (i < N) ? indeg[i] : 0;
  int x = val;
#pragma unroll
  for (int off = 1; off < 64; off <<= 1) {
    int y = __shfl_up(x, off, 64);
    if (lane >= off) x += y;
  }
  if (lane == 63) wsum[wid] = x;
  __syncthreads();
  if (wid == 0) {
    int s = (lane < 16) ? wsum[lane] : 0;
#pragma unroll
    for (int off = 1; off < 16; off <<= 1) {
      int y = __shfl_up(s, off, 64);
      if (lane >= off) s += y;
    }
    if (lane < 16) wsum[lane] = s;
  }
  __syncthreads();
  int ex = x - val + ((wid > 0) ? wsum[wid - 1] : 0);
  if (i < N) excl[i] = ex;
  if (threadIdx.x == 0) bsum[blockIdx.x] = wsum[15];
}

__global__ void scanB_k(int* __restrict__ bsum, int nb) {  // nb <= 64, one wave
  int lane = threadIdx.x;
  int v = (lane < nb) ? bsum[lane] : 0;
  int x = v;
#pragma unroll
  for (int off = 1; off < 64; off <<= 1) {
    int y = __shfl_up(x, off, 64);
    if (lane >= off) x += y;
  }
  if (lane < nb) bsum[lane] = x - v;
  if (lane == nb - 1) bsum[nb] = x;  // grand total
}

__global__ __launch_bounds__(1024) void scanC_k(const int* __restrict__ excl,
                                                const int* __restrict__ bsum,
                                                int* __restrict__ row_start,
                                                int* __restrict__ cursor, int N, int nb) {
  int i = blockIdx.x * 1024 + threadIdx.x;
  if (i < N) {
    int v = excl[i] + bsum[blockIdx.x];
    row_start[i] = v;
    cursor[i] = v;
  }
  if (i == 0) row_start[N] = bsum[nb];
}

__global__ void fill_k(const int* __restrict__ src, const int* __restrict__ dst,
                       const float* __restrict__ dinv, int* __restrict__ cursor,
                       int* __restrict__ csr_src, int* __restrict__ csr_dst,
                       float* __restrict__ csr_norm, int E) {
  int e = blockIdx.x * blockDim.x + threadIdx.x;
  if (e >= E) return;
  int d = dst[e], s = src[e];
  int p = atomicAdd(&cursor[d], 1);
  csr_src[p] = s;
  csr_dst[p] = d;
  csr_norm[p] = dinv[s] * dinv[d];
}

// ---------- weight packing into MFMA-fragment layout (hi then lo) ----------
// out[((kt*4+ks)*128 + c)*8 + j] = bf16(W[kt*32+ks*8+j][c]); lo at +K*128
__global__ void pack_k(const float* __restrict__ WA, const float* __restrict__ WB,
                       unsigned short* __restrict__ out, int K) {
  int t = blockIdx.x * blockDim.x + threadIdx.x;
  if (t >= K * 128) return;
  int k = t >> 7, c = t & 127;
  float v = WA[k * 128 + c];
  if (WB) v -= WB[k * 128 + c];
  unsigned hb = bf16_rne_bits(v);
  float lo = v - __uint_as_float(hb);
  unsigned lb = bf16_rne_bits(lo);
  int kt = k >> 5, ks = (k >> 3) & 3, j = k & 7;
  int idx = ((kt * 4 + ks) * 128 + c) * 8 + j;
  out[idx] = (unsigned short)(hb >> 16);
  out[K * 128 + idx] = (unsigned short)(lb >> 16);
}

// ---------- feature assembly: split concat(nodes, emb[cat]) to bf16 hi/lo ----------
__global__ void xcat_split_k(const float* __restrict__ nodes, const int* __restrict__ cats,
                             const float* __restrict__ emb, unsigned* __restrict__ xh,
                             unsigned* __restrict__ xl, int N) {
  int t = blockIdx.x * blockDim.x + threadIdx.x;  // N*32, 2 channels each
  if (t >= N * 32) return;
  int i = t >> 5, p = t & 31;
  float2 v = (p < 16) ? ((const float2*)nodes)[(size_t)i * 16 + p]
                      : ((const float2*)emb)[(size_t)cats[i] * 16 + (p - 16)];
  unsigned hp, lp;
  split2(v.x, v.y, hp, lp);
  xh[(size_t)i * 32 + p] = hp;
  xl[(size_t)i * 32 + p] = lp;
}

// ---------- split-bf16 MFMA GEMM: C[M x 128] = A @ B ; A row-major K, B packed ----------
__global__ __launch_bounds__(256) void gemm_mfma(const unsigned short* __restrict__ Ah,
                                                 const unsigned short* __restrict__ Al,
                                                 const unsigned short* __restrict__ Bp,
                                                 float* __restrict__ C, int M, int K) {
  __shared__ uint4 Blds[4096];  // 64KB max (K=128); K=64 uses 2048
  const int nq = K * 32;        // uint4 count (hi+lo)
  for (int i = threadIdx.x; i < nq; i += 256) Blds[i] = ((const uint4*)Bp)[i];
  __syncthreads();
  const int w = threadIdx.x >> 6, lane = threadIdx.x & 63;
  const int ks = lane >> 4, fr = lane & 15;
  const int rb0 = blockIdx.x * 128 + w * 32;
  const int loBase = K * 16;  // uint4 offset of lo half
  f32x4 acc[2][8];
#pragma unroll
  for (int m = 0; m < 2; ++m)
#pragma unroll
    for (int ct = 0; ct < 8; ++ct) acc[m][ct] = (f32x4)0.f;

  const int nkt = K >> 5;
  for (int kt = 0; kt < nkt; ++kt) {
    B8 ah[2], al[2];
#pragma unroll
    for (int m = 0; m < 2; ++m) {
      size_t off = (size_t)(rb0 + m * 16 + fr) * K + kt * 32 + ks * 8;
      ah[m].q = *(const uint4*)(Ah + off);
      al[m].q = *(const uint4*)(Al + off);
    }
#pragma unroll
    for (int ct = 0; ct < 8; ++ct) {
      int bidx = (kt * 4 + ks) * 128 + ct * 16 + fr;
      B8 bh, bl;
      bh.q = Blds[bidx];
      bl.q = Blds[bidx + loBase];
#pragma unroll
      for (int m = 0; m < 2; ++m) {
        acc[m][ct] = __builtin_amdgcn_mfma_f32_16x16x32_bf16(ah[m].v, bh.v, acc[m][ct], 0, 0, 0);
        acc[m][ct] = __builtin_amdgcn_mfma_f32_16x16x32_bf16(ah[m].v, bl.v, acc[m][ct], 0, 0, 0);
        acc[m][ct] = __builtin_amdgcn_mfma_f32_16x16x32_bf16(al[m].v, bh.v, acc[m][ct], 0, 0, 0);
      }
    }
  }
#pragma unroll
  for (int m = 0; m < 2; ++m)
#pragma unroll
    for (int ct = 0; ct < 8; ++ct) {
      int col = ct * 16 + fr;
#pragma unroll
      for (int r = 0; r < 4; ++r) {
        int row = rb0 + m * 16 + ks * 4 + r;
        if (row < M) C[(size_t)row * 128 + col] = acc[m][ct][r];
      }
    }
}

// ---------- dual GEMM (K=128): U = A@B1 + bias1, V = A@B2 ; A-frags loaded once ----------
__global__ __launch_bounds__(256) void gemm_dual_mfma(const unsigned short* __restrict__ Ah,
                                                      const unsigned short* __restrict__ Al,
                                                      const unsigned short* __restrict__ Bp1,
                                                      const unsigned short* __restrict__ Bp2,
                                                      const float* __restrict__ bias1,
                                                      float* __restrict__ U,
                                                      float* __restrict__ V, int M) {
  __shared__ uint4 Blds[4096];
  for (int i = threadIdx.x; i < 4096; i += 256) Blds[i] = ((const uint4*)Bp1)[i];
  const int w = threadIdx.x >> 6, lane = threadIdx.x & 63;
  const int ks = lane >> 4, fr = lane & 15;
  const int rb0 = blockIdx.x * 128 + w * 32;
  B8 ah[2][4], al[2][4];
#pragma unroll
  for (int m = 0; m < 2; ++m)
#pragma unroll
    for (int kt = 0; kt < 4; ++kt) {
      size_t off = (size_t)(rb0 + m * 16 + fr) * 128 + kt * 32 + ks * 8;
      ah[m][kt].q = *(const uint4*)(Ah + off);
      al[m][kt].q = *(const uint4*)(Al + off);
    }
  __syncthreads();

  f32x4 acc[2][8];
#pragma unroll
  for (int m = 0; m < 2; ++m)
#pragma unroll
    for (int ct = 0; ct < 8; ++ct) acc[m][ct] = (f32x4)0.f;
#pragma unroll
  for (int kt = 0; kt < 4; ++kt)
#pragma unroll
    for (int ct = 0; ct < 8; ++ct) {
      int bidx = (kt * 4 + ks) * 128 + ct * 16 + fr;
      B8 bh, bl;
      bh.q = Blds[bidx];
      bl.q = Blds[bidx + 2048];
#pragma unroll
      for (int m = 0; m < 2; ++m) {
        acc[m][ct] = __builtin_amdgcn_mfma_f32_16x16x32_bf16(ah[m][kt].v, bh.v, acc[m][ct], 0, 0, 0);
        acc[m][ct] = __builtin_amdgcn_mfma_f32_16x16x32_bf16(ah[m][kt].v, bl.v, acc[m][ct], 0, 0, 0);
        acc[m][ct] = __builtin_amdgcn_mfma_f32_16x16x32_bf16(al[m][kt].v, bh.v, acc[m][ct], 0, 0, 0);
      }
    }
#pragma unroll
  for (int m = 0; m < 2; ++m)
#pragma unroll
    for (int ct = 0; ct < 8; ++ct) {
      int col = ct * 16 + fr;
      float bv = bias1[col];
#pragma unroll
      for (int r = 0; r < 4; ++r) {
        int row = rb0 + m * 16 + ks * 4 + r;
        if (row < M) U[(size_t)row * 128 + col] = acc[m][ct][r] + bv;
      }
    }

  __syncthreads();  // all pass-1 LDS reads done
  for (int i = threadIdx.x; i < 4096; i += 256) Blds[i] = ((const uint4*)Bp2)[i];
  __syncthreads();

#pragma unroll
  for (int m = 0; m < 2; ++m)
#pragma unroll
    for (int ct = 0; ct < 8; ++ct) acc[m][ct] = (f32x4)0.f;
#pragma unroll
  for (int kt = 0; kt < 4; ++kt)
#pragma unroll
    for (int ct = 0; ct < 8; ++ct) {
      int bidx = (kt * 4 + ks) * 128 + ct * 16 + fr;
      B8 bh, bl;
      bh.q = Blds[bidx];
      bl.q = Blds[bidx + 2048];
#pragma unroll
      for (int m = 0; m < 2; ++m) {
        acc[m][ct] = __builtin_amdgcn_mfma_f32_16x16x32_bf16(ah[m][kt].v, bh.v, acc[m][ct], 0, 0, 0);
        acc[m][ct] = __builtin_amdgcn_mfma_f32_16x16x32_bf16(ah[m][kt].v, bl.v, acc[m][ct], 0, 0, 0);
        acc[m][ct] = __builtin_amdgcn_mfma_f32_16x16x32_bf16(al[m][kt].v, bh.v, acc[m][ct], 0, 0, 0);
      }
    }
#pragma unroll
  for (int m = 0; m < 2; ++m)
#pragma unroll
    for (int ct = 0; ct < 8; ++ct) {
      int col = ct * 16 + fr;
#pragma unroll
      for (int r = 0; r < 4; ++r) {
        int row = rb0 + m * 16 + ks * 4 + r;
        if (row < M) V[(size_t)row * 128 + col] = acc[m][ct][r];
      }
    }
}

// ---------- GCN aggregate + relu + split to bf16 hi/lo ----------
// wave = 1 node; 8 lane-groups of 8 process neighbors mod-8; 16 ch/lane (4xfloat4);
// explicit next-index prefetch breaks the idx->row dependent chain.
__global__ __launch_bounds__(256) void gcn_agg_split_k(
    const float* __restrict__ h, const int* __restrict__ csr_src,
    const float* __restrict__ csr_norm, const int* __restrict__ row_start,
    const float* __restrict__ dinv, const float* __restrict__ bias,
    unsigned* __restrict__ out_hi, unsigned* __restrict__ out_lo, int N) {
  int i = (blockIdx.x * blockDim.x + threadIdx.x) >> 6;
  int lane = threadIdx.x & 63;
  if (i >= N) return;
  const int g = lane >> 3, c = (lane & 7) * 16;
  float4 a0 = make_float4(0.f, 0.f, 0.f, 0.f);
  float4 a1 = a0, a2 = a0, a3 = a0;
  int s0 = row_start[i], s1 = row_start[i + 1];
  if (g == 0) {  // self term
    float di = dinv[i];
    float sn = di * di;
    const float4* hp = (const float4*)&h[(size_t)i * 128 + c];
    float4 v0 = hp[0], v1 = hp[1], v2 = hp[2], v3 = hp[3];
    a0.x = v0.x * sn; a0.y = v0.y * sn; a0.z = v0.z * sn; a0.w = v0.w * sn;
    a1.x = v1.x * sn; a1.y = v1.y * sn; a1.z = v1.z * sn; a1.w = v1.w * sn;
    a2.x = v2.x * sn; a2.y = v2.y * sn; a2.z = v2.z * sn; a2.w = v2.w * sn;
    a3.x = v3.x * sn; a3.y = v3.y * sn; a3.z = v3.z * sn; a3.w = v3.w * sn;
  }
  int p = s0 + g;
  int sC = 0; float wC = 0.f;
  if (p < s1) { sC = csr_src[p]; wC = csr_norm[p]; }
  for (; p < s1; p += 8) {
    int pn = p + 8;
    int sN = 0; float wN = 0.f;
    if (pn < s1) { sN = csr_src[pn]; wN = csr_norm[pn]; }  // prefetch next idx
    const float4* hp = (const float4*)&h[(size_t)sC * 128 + c];
    float4 h0 = hp[0], h1 = hp[1], h2 = hp[2], h3 = hp[3];
    a0.x = fmaf(h0.x, wC, a0.x); a0.y = fmaf(h0.y, wC, a0.y);
    a0.z = fmaf(h0.z, wC, a0.z); a0.w = fmaf(h0.w, wC, a0.w);
    a1.x = fmaf(h1.x, wC, a1.x); a1.y = fmaf(h1.y, wC, a1.y);
    a1.z = fmaf(h1.z, wC, a1.z); a1.w = fmaf(h1.w, wC, a1.w);
    a2.x = fmaf(h2.x, wC, a2.x); a2.y = fmaf(h2.y, wC, a2.y);
    a2.z = fmaf(h2.z, wC, a2.z); a2.w = fmaf(h2.w, wC, a2.w);
    a3.x = fmaf(h3.x, wC, a3.x); a3.y = fmaf(h3.y, wC, a3.y);
    a3.z = fmaf(h3.z, wC, a3.z); a3.w = fmaf(h3.w, wC, a3.w);
    sC = sN; wC = wN;
  }
  // combine across 8 groups (lanes differing in bits 3,4,5)
#pragma unroll
  for (int off = 8; off < 64; off <<= 1) {
    a0.x += __shfl_xor(a0.x, off); a0.y += __shfl_xor(a0.y, off);
    a0.z += __shfl_xor(a0.z, off); a0.w += __shfl_xor(a0.w, off);
    a1.x += __shfl_xor(a1.x, off); a1.y += __shfl_xor(a1.y, off);
    a1.z += __shfl_xor(a1.z, off); a1.w += __shfl_xor(a1.w, off);
    a2.x += __shfl_xor(a2.x, off); a2.y += __shfl_xor(a2.y, off);
    a2.z += __shfl_xor(a2.z, off); a2.w += __shfl_xor(a2.w, off);
    a3.x += __shfl_xor(a3.x, off); a3.y += __shfl_xor(a3.y, off);
    a3.z += __shfl_xor(a3.z, off); a3.w += __shfl_xor(a3.w, off);
  }
  if (g == 0) {
    const float4* bp = (const float4*)&bias[c];
    float4 b0 = bp[0], b1 = bp[1], b2 = bp[2], b3 = bp[3];
    float v0 = fmaxf(a0.x + b0.x, 0.f), v1 = fmaxf(a0.y + b0.y, 0.f);
    float v2 = fmaxf(a0.z + b0.z, 0.f), v3 = fmaxf(a0.w + b0.w, 0.f);
    float v4 = fmaxf(a1.x + b1.x, 0.f), v5 = fmaxf(a1.y + b1.y, 0.f);
    float v6 = fmaxf(a1.z + b1.z, 0.f), v7 = fmaxf(a1.w + b1.w, 0.f);
    float v8 = fmaxf(a2.x + b2.x, 0.f), v9 = fmaxf(a2.y + b2.y, 0.f);
    float va = fmaxf(a2.z + b2.z, 0.f), vb = fmaxf(a2.w + b2.w, 0.f);
    float vc = fmaxf(a3.x + b3.x, 0.f), vd = fmaxf(a3.y + b3.y, 0.f);
    float ve = fmaxf(a3.z + b3.z, 0.f), vf = fmaxf(a3.w + b3.w, 0.f);
    uint4 hh0, ll0, hh1, ll1;
    split2(v0, v1, hh0.x, ll0.x); split2(v2, v3, hh0.y, ll0.y);
    split2(v4, v5, hh0.z, ll0.z); split2(v6, v7, hh0.w, ll0.w);
    split2(v8, v9, hh1.x, ll1.x); split2(va, vb, hh1.y, ll1.y);
    split2(vc, vd, hh1.z, ll1.z); split2(ve, vf, hh1.w, ll1.w);
    size_t base = (size_t)i * 64 + (lane & 7) * 8;
    *(uint4*)&out_hi[base] = hh0;
    *(uint4*)&out_hi[base + 4] = hh1;
    *(uint4*)&out_lo[base] = ll0;
    *(uint4*)&out_lo[base + 4] = ll1;
  }
}

// ---------- EdgeConv: MFMA split-bf16, double-buffered kt pipeline, run-length max ----------
// 256 threads / 128-edge tiles, interleaved grid-stride (R3 occupancy sweet spot).
// be1 pre-folded into U. VGPR budget free up to 256 (LDS caps occupancy at 2 waves/SIMD).
__global__ __launch_bounds__(256, 2) void edgeconv_mfma(
    const float* __restrict__ U, const float* __restrict__ V,
    const int* __restrict__ csr_src, const int* __restrict__ csr_dst,
    const unsigned short* __restrict__ We2p, const float* __restrict__ be2,
    unsigned* __restrict__ agg, int E, int ntiles) {
  __shared__ uint4 Blds[4096];  // We2 hi (2048) + lo (2048)
  for (int i = threadIdx.x; i < 4096; i += 256) Blds[i] = ((const uint4*)We2p)[i];
  __syncthreads();
  const int w = threadIdx.x >> 6, lane = threadIdx.x & 63;
  const int ks = lane >> 4, fr = lane & 15;
  float b2[8];
#pragma unroll
  for (int ct = 0; ct < 8; ++ct) b2[ct] = be2[ct * 16 + fr];

  auto loadIdx = [&](int t, int (&d)[2], int (&s)[2]) {
    const int eb = t * 128 + w * 32;
#pragma unroll
    for (int m = 0; m < 2; ++m) {
      int el = ((fr >> 2) << 3) + (m << 2) + (fr & 3);
      int e = eb + el;
      int ee = (e < E) ? e : 0;
      d[m] = csr_dst[ee];
      s[m] = csr_src[ee];
    }
  };

  int tile = blockIdx.x;
  int dA[2] = {0, 0}, sA[2] = {0, 0};
  if (tile < ntiles) loadIdx(tile, dA, sA);

  for (; tile < ntiles; tile += gridDim.x) {
    const int eb = tile * 128 + w * 32;
    int dN[2] = {0, 0}, sN[2] = {0, 0};
    const int tn = tile + gridDim.x;
    if (tn < ntiles) loadIdx(tn, dN, sN);  // next-tile index prefetch

    f32x4 acc[2][8];
#pragma unroll
    for (int m = 0; m < 2; ++m)
#pragma unroll
      for (int ct = 0; ct < 8; ++ct) acc[m][ct] = (f32x4)0.f;

    // double-buffered raw U/V rows: [buf][m][half]
    float4 ru[2][2][2], rv[2][2][2];
    {
      const int k0 = ks * 8;
#pragma unroll
      for (int m = 0; m < 2; ++m) {
        const float4* up = (const float4*)&U[(size_t)dA[m] * 128 + k0];
        const float4* vp = (const float4*)&V[(size_t)sA[m] * 128 + k0];
        ru[0][m][0] = up[0]; ru[0][m][1] = up[1];
        rv[0][m][0] = vp[0]; rv[0][m][1] = vp[1];
      }
    }
#pragma unroll
    for (int kt = 0; kt < 4; ++kt) {
      const int cb = kt & 1, nb = cb ^ 1;
      if (kt < 3) {  // issue next kt's loads before compute
        const int k0n = (kt + 1) * 32 + ks * 8;
#pragma unroll
        for (int m = 0; m < 2; ++m) {
          const float4* up = (const float4*)&U[(size_t)dA[m] * 128 + k0n];
          const float4* vp = (const float4*)&V[(size_t)sA[m] * 128 + k0n];
          ru[nb][m][0] = up[0]; ru[nb][m][1] = up[1];
          rv[nb][m][0] = vp[0]; rv[nb][m][1] = vp[1];
        }
      }
      B8 ah[2], al[2];
#pragma unroll
      for (int m = 0; m < 2; ++m) {
        float4 u0 = ru[cb][m][0], u1 = ru[cb][m][1];
        float4 v0 = rv[cb][m][0], v1 = rv[cb][m][1];
        float s0 = fmaxf(u0.x + v0.x, 0.f);
        float s1 = fmaxf(u0.y + v0.y, 0.f);
        float s2 = fmaxf(u0.z + v0.z, 0.f);
        float s3 = fmaxf(u0.w + v0.w, 0.f);
        float s4 = fmaxf(u1.x + v1.x, 0.f);
        float s5 = fmaxf(u1.y + v1.y, 0.f);
        float s6 = fmaxf(u1.z + v1.z, 0.f);
        float s7 = fmaxf(u1.w + v1.w, 0.f);
        split2(s0, s1, ah[m].u[0], al[m].u[0]);
        split2(s2, s3, ah[m].u[1], al[m].u[1]);
        split2(s4, s5, ah[m].u[2], al[m].u[2]);
        split2(s6, s7, ah[m].u[3], al[m].u[3]);
      }
      __builtin_amdgcn_s_setprio(1);
#pragma unroll
      for (int ct = 0; ct < 8; ++ct) {
        int bidx = (kt * 4 + ks) * 128 + ct * 16 + fr;
        B8 bh, bl;
        bh.q = Blds[bidx];
        bl.q = Blds[bidx + 2048];
#pragma unroll
        for (int m = 0; m < 2; ++m) {
          acc[m][ct] = __builtin_amdgcn_mfma_f32_16x16x32_bf16(ah[m].v, bh.v, acc[m][ct], 0, 0, 0);
          acc[m][ct] = __builtin_amdgcn_mfma_f32_16x16x32_bf16(ah[m].v, bl.v, acc[m][ct], 0, 0, 0);
          acc[m][ct] = __builtin_amdgcn_mfma_f32_16x16x32_bf16(al[m].v, bh.v, acc[m][ct], 0, 0, 0);
        }
      }
      __builtin_amdgcn_s_setprio(0);
    }
    // epilogue: lane's 8 consecutive edges = (m,r) regs; run-length max, relu-first atomicMax
    const int ebase = eb + ks * 8;
    int prev = -1;
    float runv[8];
#pragma unroll
    for (int j = 0; j < 8; ++j) {
      int e = ebase + j;
      if (e < E) {
        int d = csr_dst[e];
        const int m = j >> 2, r = j & 3;
        if (d != prev) {
          if (prev >= 0) {
#pragma unroll
            for (int ct = 0; ct < 8; ++ct)
              atomicMax(&agg[(size_t)prev * 128 + ct * 16 + fr], __float_as_uint(runv[ct]));
          }
          prev = d;
#pragma unroll
          for (int ct = 0; ct < 8; ++ct) runv[ct] = fmaxf(acc[m][ct][r] + b2[ct], 0.f);
        } else {
#pragma unroll
          for (int ct = 0; ct < 8; ++ct)
            runv[ct] = fmaxf(runv[ct], fmaxf(acc[m][ct][r] + b2[ct], 0.f));
        }
      }
    }
    if (prev >= 0) {
#pragma unroll
      for (int ct = 0; ct < 8; ++ct)
        atomicMax(&agg[(size_t)prev * 128 + ct * 16 + fr], __float_as_uint(runv[ct]));
    }
    dA[0] = dN[0]; dA[1] = dN[1];
    sA[0] = sN[0]; sA[1] = sN[1];
  }
}

// ---------- graph boundaries (batch is sorted) ----------
__global__ void gbound_k(const int* __restrict__ batch, int* __restrict__ gstart, int N) {
  int g = threadIdx.x;
  if (g > NGRAPHS) return;
  if (g == NGRAPHS) { gstart[NGRAPHS] = N; return; }
  int lo = 0, hi = N;
  while (lo < hi) {
    int mid = (lo + hi) >> 1;
    if (batch[mid] < g) lo = mid + 1; else hi = mid;
  }
  gstart[g] = lo;
}

// ---------- segmented pooling: grid = NGRAPHS*8, one atomic pair per (block,channel) ----------
__global__ __launch_bounds__(256) void pool_seg_k(const float* __restrict__ x,
                                                  const int* __restrict__ gstart,
                                                  unsigned* __restrict__ gmax,
                                                  float* __restrict__ gsum) {
  int g = blockIdx.x >> 3, s = blockIdx.x & 7;
  int lb = gstart[g], ub = gstart[g + 1];
  long len = ub - lb;
  int i0 = lb + (int)((len * s) >> 3);
  int i1 = lb + (int)((len * (s + 1)) >> 3);
  int c = threadIdx.x & 127, h = threadIdx.x >> 7;
  float m = 0.f, sm = 0.f;
  for (int i = i0 + h; i < i1; i += 2) {
    float v = x[(size_t)i * 128 + c];
    m = fmaxf(m, v);
    sm += v;
  }
  if (i1 > i0) {
    atomicMax(&gmax[g * 128 + c], __float_as_uint(m));
    atomicAdd(&gsum[g * 128 + c], sm);
  }
}

__global__ void g0_k(const unsigned* __restrict__ gmax, const float* __restrict__ gsum,
                     const int* __restrict__ gstart, float* __restrict__ g0) {
  int t = blockIdx.x * blockDim.x + threadIdx.x;  // 64*256
  int g = t >> 8, c = t & 255;
  float o;
  if (c < 128) o = __uint_as_float(gmax[g * 128 + c]);
  else {
    float cnt = (float)(gstart[g + 1] - gstart[g]);
    o = gsum[g * 128 + (c - 128)] / fmaxf(cnt, 1.f);
  }
  g0[t] = o;
}

// ---------- head FC (relu) ----------
__global__ __launch_bounds__(256) void fc_k(const float* __restrict__ X,
                                            const float* __restrict__ W,
                                            const float* __restrict__ b,
                                            float* __restrict__ Y, int K, int N) {
  __shared__ float xs[256];
  int g = blockIdx.x, c = threadIdx.x;
  for (int k = c; k < K; k += blockDim.x) xs[k] = X[g * K + k];
  __syncthreads();
  float acc = b[c];
  for (int k = 0; k < K; k++) acc = fmaf(xs[k], W[(size_t)k * N + c], acc);
  Y[g * N + c] = fmaxf(acc, 0.f);
}

// ---------- launch ----------
extern "C" void kernel_launch(void* const* d_in, const int* in_sizes, int n_in,
                              void* d_out, int out_size, void* d_ws, size_t ws_size,
                              hipStream_t stream) {
  const float* nodes = (const float*)d_in[0];
  const int* cats = (const int*)d_in[1];
  const int* eidx = (const int*)d_in[2];
  const int* batch = (const int*)d_in[3];
  const float* emb = (const float*)d_in[4];
  const float* W1 = (const float*)d_in[5];
  const float* b1 = (const float*)d_in[6];
  const float* W2 = (const float*)d_in[7];
  const float* b2 = (const float*)d_in[8];
  const float* W3 = (const float*)d_in[9];
  const float* b3 = (const float*)d_in[10];
  const float* We1 = (const float*)d_in[11];
  const float* be1 = (const float*)d_in[12];
  const float* We2 = (const float*)d_in[13];
  const float* be2 = (const float*)d_in[14];
  const float* Wf1 = (const float*)d_in[15];
  const float* bf1 = (const float*)d_in[16];
  const float* Wf2 = (const float*)d_in[17];
  const float* bf2 = (const float*)d_in[18];
  float* out = (float*)d_out;

  const int N = in_sizes[0] / FEAT;
  const int E = in_sizes[2] / 2;
  const int Npad = ((N + 127) / 128) * 128;
  const int* src = eidx;
  const int* dst = eidx + E;

  char* w = (char*)d_ws;
  auto alloc = [&](size_t bytes) -> void* {
    void* p = (void*)w;
    w += (bytes + 255) & ~(size_t)255;
    return p;
  };
  unsigned* xh = (unsigned*)alloc((size_t)Npad * 32 * 4);   // [Npad x 64] bf16 pairs
  unsigned* xl = (unsigned*)alloc((size_t)Npad * 32 * 4);
  unsigned* ahb = (unsigned*)alloc((size_t)Npad * 64 * 4);  // [Npad x 128] bf16 pairs
  unsigned* alb = (unsigned*)alloc((size_t)Npad * 64 * 4);
  float* bufF = (float*)alloc((size_t)Npad * 128 * 4);      // gemm out / U
  float* bufV = (float*)alloc((size_t)Npad * 128 * 4);
  unsigned* agg = (unsigned*)alloc((size_t)N * 128 * 4);
  int* indeg = (int*)alloc((size_t)N * 4);
  int* rowst = (int*)alloc((size_t)(N + 1) * 4);
  int* cursor = (int*)alloc((size_t)N * 4);
  int* exclb = (int*)alloc((size_t)N * 4);
  int* bsum = (int*)alloc(128 * 4);
  float* dinv = (float*)alloc((size_t)N * 4);
  int* csr_src = (int*)alloc((size_t)E * 4);
  int* csr_dst = (int*)alloc((size_t)E * 4);
  float* csr_norm = (float*)alloc((size_t)E * 4);
  unsigned short* W1p = (unsigned short*)alloc(2 * 64 * 128 * 2);
  unsigned short* W2p = (unsigned short*)alloc(2 * 128 * 128 * 2);
  unsigned short* W3p = (unsigned short*)alloc(2 * 128 * 128 * 2);
  unsigned short* Wdp = (unsigned short*)alloc(2 * 128 * 128 * 2);
  unsigned short* Wvp = (unsigned short*)alloc(2 * 128 * 128 * 2);
  unsigned short* We2p = (unsigned short*)alloc(2 * 128 * 128 * 2);
  float* g0buf = (float*)alloc(NGRAPHS * 256 * 4);
  float* g1buf = (float*)alloc(NGRAPHS * 256 * 4);
  unsigned* gmax = (unsigned*)alloc(NGRAPHS * 128 * 4);
  float* gsum = (float*)alloc(NGRAPHS * 128 * 4);
  int* gstart = (int*)alloc((NGRAPHS + 1) * 4);
  if ((size_t)(w - (char*)d_ws) > ws_size) return;

  hipMemsetAsync(indeg, 0, (size_t)N * 4, stream);
  hipMemsetAsync(agg, 0, (size_t)N * 128 * 4, stream);
  hipMemsetAsync(gmax, 0, NGRAPHS * 128 * 4, stream);
  hipMemsetAsync(gsum, 0, NGRAPHS * 128 * 4, stream);

  const int TB = 256;
  int gE = (E + TB - 1) / TB;
  int gN = (N + TB - 1) / TB;
  int nb = (N + 1023) / 1024;

  hist_k<<<gE, TB, 0, stream>>>(dst, indeg, E);
  dinv_k<<<gN, TB, 0, stream>>>(indeg, dinv, N);
  scanA_k<<<nb, 1024, 0, stream>>>(indeg, exclb, bsum, N);
  scanB_k<<<1, 64, 0, stream>>>(bsum, nb);
  scanC_k<<<nb, 1024, 0, stream>>>(exclb, bsum, rowst, cursor, N, nb);
  fill_k<<<gE, TB, 0, stream>>>(src, dst, dinv, cursor, csr_src, csr_dst, csr_norm, E);
  gbound_k<<<1, 128, 0, stream>>>(batch, gstart, N);

  xcat_split_k<<<(N * 32 + TB - 1) / TB, TB, 0, stream>>>(nodes, cats, emb, xh, xl, N);

  pack_k<<<32, TB, 0, stream>>>(W1, nullptr, W1p, 64);
  pack_k<<<64, TB, 0, stream>>>(W2, nullptr, W2p, 128);
  pack_k<<<64, TB, 0, stream>>>(W3, nullptr, W3p, 128);
  pack_k<<<64, TB, 0, stream>>>(We1, We1 + 128 * 128, Wdp, 128);  // top - bot
  pack_k<<<64, TB, 0, stream>>>(We1 + 128 * 128, nullptr, Wvp, 128);
  pack_k<<<64, TB, 0, stream>>>(We2, nullptr, We2p, 128);

  const int gemmGrid = Npad / 128;
  const int waveGrid = (N * 64 + TB - 1) / TB;

  gemm_mfma<<<gemmGrid, TB, 0, stream>>>((unsigned short*)xh, (unsigned short*)xl, W1p, bufF, N, 64);
  gcn_agg_split_k<<<waveGrid, TB, 0, stream>>>(bufF, csr_src, csr_norm, rowst, dinv, b1, ahb, alb, N);
  gemm_mfma<<<gemmGrid, TB, 0, stream>>>((unsigned short*)ahb, (unsigned short*)alb, W2p, bufF, N, 128);
  gcn_agg_split_k<<<waveGrid, TB, 0, stream>>>(bufF, csr_src, csr_norm, rowst, dinv, b2, ahb, alb, N);
  gemm_mfma<<<gemmGrid, TB, 0, stream>>>((unsigned short*)ahb, (unsigned short*)alb, W3p, bufF, N, 128);
  gcn_agg_split_k<<<waveGrid, TB, 0, stream>>>(bufF, csr_src, csr_norm, rowst, dinv, b3, ahb, alb, N);

  // EdgeConv precompute: U = x3 @ (We1_top - We1_bot) + be1, V = x3 @ We1_bot (fused)
  gemm_dual_mfma<<<gemmGrid, TB, 0, stream>>>((unsigned short*)ahb, (unsigned short*)alb,
                                              Wdp, Wvp, be1, bufF, bufV, N);

  const int ntiles = (E + 127) / 128;
  edgeconv_mfma<<<2048, TB, 0, stream>>>(bufF, bufV, csr_src, csr_dst, We2p, be2, agg, E, ntiles);

  pool_seg_k<<<NGRAPHS * 8, TB, 0, stream>>>((const float*)agg, gstart, gmax, gsum);
  g0_k<<<NGRAPHS, TB, 0, stream>>>(gmax, gsum, gstart, g0buf);
  fc_k<<<NGRAPHS, 256, 0, stream>>>(g0buf, Wf1, bf1, g1buf, 256, 256);
  fc_k<<<NGRAPHS, 256, 0, stream>>>(g1buf, Wf2, bf2, out, 256, 256);
}

// Round 8
// 715.274 us; speedup vs baseline: 1.2494x; 1.2494x over previous
//
#include <hip/hip_runtime.h>

#define FEAT 32
#define EMB 32
#define HID 128
#define NGRAPHS 64

typedef short short8 __attribute__((ext_vector_type(8)));
typedef float f32x4 __attribute__((ext_vector_type(4)));

union B8 { uint4 q; unsigned u[4]; short8 v; };

// round-to-nearest-even bf16, returned as f32 bits with low16 zeroed
__device__ __forceinline__ unsigned bf16_rne_bits(float f) {
  unsigned u = __float_as_uint(f);
  unsigned r = u + 0x7FFFu + ((u >> 16) & 1u);
  return r & 0xFFFF0000u;
}
// split a,b (f32) into packed bf16 hi-pair and lo-pair (elem0 low16, elem1 high16)
__device__ __forceinline__ void split2(float a, float b, unsigned& hp, unsigned& lp) {
  unsigned ha = bf16_rne_bits(a), hb = bf16_rne_bits(b);
  float la = a - __uint_as_float(ha), lb = b - __uint_as_float(hb);
  unsigned laa = bf16_rne_bits(la), lbb = bf16_rne_bits(lb);
  hp = (ha >> 16) | (hb & 0xFFFF0000u);
  lp = (laa >> 16) | (lbb & 0xFFFF0000u);
}

// ---------- CSR build ----------
__global__ void hist_k(const int* __restrict__ dst, int* __restrict__ indeg, int E) {
  int e = blockIdx.x * blockDim.x + threadIdx.x;
  if (e < E) atomicAdd(&indeg[dst[e]], 1);
}

__global__ void dinv_k(const int* __restrict__ indeg, float* __restrict__ dinv, int N) {
  int i = blockIdx.x * blockDim.x + threadIdx.x;
  if (i < N) dinv[i] = rsqrtf((float)indeg[i] + 1.0f);  // +1 self loop
}

// ---------- parallel 3-phase exclusive scan of indeg ----------
__global__ __launch_bounds__(1024) void scanA_k(const int* __restrict__ indeg,
                                                int* __restrict__ excl,
                                                int* __restrict__ bsum, int N) {
  __shared__ int wsum[16];
  int i = blockIdx.x * 1024 + threadIdx.x;
  const int lane = threadIdx.x & 63;
  const int wid = threadIdx.x >> 6;
  int val = (i < N) ? indeg[i] : 0;
  int x = val;
#pragma unroll
  for (int off = 1; off < 64; off <<= 1) {
    int y = __shfl_up(x, off, 64);
    if (lane >= off) x += y;
  }
  if (lane == 63) wsum[wid] = x;
  __syncthreads();
  if (wid == 0) {
    int s = (lane < 16) ? wsum[lane] : 0;
#pragma unroll
    for (int off = 1; off < 16; off <<= 1) {
      int y = __shfl_up(s, off, 64);
      if (lane >= off) s += y;
    }
    if (lane < 16) wsum[lane] = s;
  }
  __syncthreads();
  int ex = x - val + ((wid > 0) ? wsum[wid - 1] : 0);
  if (i < N) excl[i] = ex;
  if (threadIdx.x == 0) bsum[blockIdx.x] = wsum[15];
}

__global__ void scanB_k(int* __restrict__ bsum, int nb) {  // nb <= 64, one wave
  int lane = threadIdx.x;
  int v = (lane < nb) ? bsum[lane] : 0;
  int x = v;
#pragma unroll
  for (int off = 1; off < 64; off <<= 1) {
    int y = __shfl_up(x, off, 64);
    if (lane >= off) x += y;
  }
  if (lane < nb) bsum[lane] = x - v;
  if (lane == nb - 1) bsum[nb] = x;  // grand total
}

__global__ __launch_bounds__(1024) void scanC_k(const int* __restrict__ excl,
                                                const int* __restrict__ bsum,
                                                int* __restrict__ row_start,
                                                int* __restrict__ cursor, int N, int nb) {
  int i = blockIdx.x * 1024 + threadIdx.x;
  if (i < N) {
    int v = excl[i] + bsum[blockIdx.x];
    row_start[i] = v;
    cursor[i] = v;
  }
  if (i == 0) row_start[N] = bsum[nb];
}

__global__ void fill_k(const int* __restrict__ src, const int* __restrict__ dst,
                       const float* __restrict__ dinv, int* __restrict__ cursor,
                       int* __restrict__ csr_src, int* __restrict__ csr_dst,
                       float* __restrict__ csr_norm, int E) {
  int e = blockIdx.x * blockDim.x + threadIdx.x;
  if (e >= E) return;
  int d = dst[e], s = src[e];
  int p = atomicAdd(&cursor[d], 1);
  csr_src[p] = s;
  csr_dst[p] = d;
  csr_norm[p] = dinv[s] * dinv[d];
}

// ---------- weight packing into MFMA-fragment layout (hi then lo) ----------
// out[((kt*4+ks)*128 + c)*8 + j] = bf16(W[kt*32+ks*8+j][c]); lo at +K*128
__global__ void pack_k(const float* __restrict__ WA, const float* __restrict__ WB,
                       unsigned short* __restrict__ out, int K) {
  int t = blockIdx.x * blockDim.x + threadIdx.x;
  if (t >= K * 128) return;
  int k = t >> 7, c = t & 127;
  float v = WA[k * 128 + c];
  if (WB) v -= WB[k * 128 + c];
  unsigned hb = bf16_rne_bits(v);
  float lo = v - __uint_as_float(hb);
  unsigned lb = bf16_rne_bits(lo);
  int kt = k >> 5, ks = (k >> 3) & 3, j = k & 7;
  int idx = ((kt * 4 + ks) * 128 + c) * 8 + j;
  out[idx] = (unsigned short)(hb >> 16);
  out[K * 128 + idx] = (unsigned short)(lb >> 16);
}

// ---------- feature assembly: split concat(nodes, emb[cat]) to bf16 hi/lo ----------
__global__ void xcat_split_k(const float* __restrict__ nodes, const int* __restrict__ cats,
                             const float* __restrict__ emb, unsigned* __restrict__ xh,
                             unsigned* __restrict__ xl, int N) {
  int t = blockIdx.x * blockDim.x + threadIdx.x;  // N*32, 2 channels each
  if (t >= N * 32) return;
  int i = t >> 5, p = t & 31;
  float2 v = (p < 16) ? ((const float2*)nodes)[(size_t)i * 16 + p]
                      : ((const float2*)emb)[(size_t)cats[i] * 16 + (p - 16)];
  unsigned hp, lp;
  split2(v.x, v.y, hp, lp);
  xh[(size_t)i * 32 + p] = hp;
  xl[(size_t)i * 32 + p] = lp;
}

// ---------- split-bf16 MFMA GEMM: C[M x 128] = A @ B ; A row-major K, B packed ----------
__global__ __launch_bounds__(256) void gemm_mfma(const unsigned short* __restrict__ Ah,
                                                 const unsigned short* __restrict__ Al,
                                                 const unsigned short* __restrict__ Bp,
                                                 float* __restrict__ C, int M, int K) {
  __shared__ uint4 Blds[4096];  // 64KB max (K=128); K=64 uses 2048
  const int nq = K * 32;        // uint4 count (hi+lo)
  for (int i = threadIdx.x; i < nq; i += 256) Blds[i] = ((const uint4*)Bp)[i];
  __syncthreads();
  const int w = threadIdx.x >> 6, lane = threadIdx.x & 63;
  const int ks = lane >> 4, fr = lane & 15;
  const int rb0 = blockIdx.x * 128 + w * 32;
  const int loBase = K * 16;  // uint4 offset of lo half
  f32x4 acc[2][8];
#pragma unroll
  for (int m = 0; m < 2; ++m)
#pragma unroll
    for (int ct = 0; ct < 8; ++ct) acc[m][ct] = (f32x4)0.f;

  const int nkt = K >> 5;
  for (int kt = 0; kt < nkt; ++kt) {
    B8 ah[2], al[2];
#pragma unroll
    for (int m = 0; m < 2; ++m) {
      size_t off = (size_t)(rb0 + m * 16 + fr) * K + kt * 32 + ks * 8;
      ah[m].q = *(const uint4*)(Ah + off);
      al[m].q = *(const uint4*)(Al + off);
    }
#pragma unroll
    for (int ct = 0; ct < 8; ++ct) {
      int bidx = (kt * 4 + ks) * 128 + ct * 16 + fr;
      B8 bh, bl;
      bh.q = Blds[bidx];
      bl.q = Blds[bidx + loBase];
#pragma unroll
      for (int m = 0; m < 2; ++m) {
        acc[m][ct] = __builtin_amdgcn_mfma_f32_16x16x32_bf16(ah[m].v, bh.v, acc[m][ct], 0, 0, 0);
        acc[m][ct] = __builtin_amdgcn_mfma_f32_16x16x32_bf16(ah[m].v, bl.v, acc[m][ct], 0, 0, 0);
        acc[m][ct] = __builtin_amdgcn_mfma_f32_16x16x32_bf16(al[m].v, bh.v, acc[m][ct], 0, 0, 0);
      }
    }
  }
#pragma unroll
  for (int m = 0; m < 2; ++m)
#pragma unroll
    for (int ct = 0; ct < 8; ++ct) {
      int col = ct * 16 + fr;
#pragma unroll
      for (int r = 0; r < 4; ++r) {
        int row = rb0 + m * 16 + ks * 4 + r;
        if (row < M) C[(size_t)row * 128 + col] = acc[m][ct][r];
      }
    }
}

// ---------- dual GEMM (K=128): U = A@B1 + bias1, V = A@B2 ; A-frags loaded once ----------
__global__ __launch_bounds__(256) void gemm_dual_mfma(const unsigned short* __restrict__ Ah,
                                                      const unsigned short* __restrict__ Al,
                                                      const unsigned short* __restrict__ Bp1,
                                                      const unsigned short* __restrict__ Bp2,
                                                      const float* __restrict__ bias1,
                                                      float* __restrict__ U,
                                                      float* __restrict__ V, int M) {
  __shared__ uint4 Blds[4096];
  for (int i = threadIdx.x; i < 4096; i += 256) Blds[i] = ((const uint4*)Bp1)[i];
  const int w = threadIdx.x >> 6, lane = threadIdx.x & 63;
  const int ks = lane >> 4, fr = lane & 15;
  const int rb0 = blockIdx.x * 128 + w * 32;
  B8 ah[2][4], al[2][4];
#pragma unroll
  for (int m = 0; m < 2; ++m)
#pragma unroll
    for (int kt = 0; kt < 4; ++kt) {
      size_t off = (size_t)(rb0 + m * 16 + fr) * 128 + kt * 32 + ks * 8;
      ah[m][kt].q = *(const uint4*)(Ah + off);
      al[m][kt].q = *(const uint4*)(Al + off);
    }
  __syncthreads();

  f32x4 acc[2][8];
#pragma unroll
  for (int m = 0; m < 2; ++m)
#pragma unroll
    for (int ct = 0; ct < 8; ++ct) acc[m][ct] = (f32x4)0.f;
#pragma unroll
  for (int kt = 0; kt < 4; ++kt)
#pragma unroll
    for (int ct = 0; ct < 8; ++ct) {
      int bidx = (kt * 4 + ks) * 128 + ct * 16 + fr;
      B8 bh, bl;
      bh.q = Blds[bidx];
      bl.q = Blds[bidx + 2048];
#pragma unroll
      for (int m = 0; m < 2; ++m) {
        acc[m][ct] = __builtin_amdgcn_mfma_f32_16x16x32_bf16(ah[m][kt].v, bh.v, acc[m][ct], 0, 0, 0);
        acc[m][ct] = __builtin_amdgcn_mfma_f32_16x16x32_bf16(ah[m][kt].v, bl.v, acc[m][ct], 0, 0, 0);
        acc[m][ct] = __builtin_amdgcn_mfma_f32_16x16x32_bf16(al[m][kt].v, bh.v, acc[m][ct], 0, 0, 0);
      }
    }
#pragma unroll
  for (int m = 0; m < 2; ++m)
#pragma unroll
    for (int ct = 0; ct < 8; ++ct) {
      int col = ct * 16 + fr;
      float bv = bias1[col];
#pragma unroll
      for (int r = 0; r < 4; ++r) {
        int row = rb0 + m * 16 + ks * 4 + r;
        if (row < M) U[(size_t)row * 128 + col] = acc[m][ct][r] + bv;
      }
    }

  __syncthreads();  // all pass-1 LDS reads done
  for (int i = threadIdx.x; i < 4096; i += 256) Blds[i] = ((const uint4*)Bp2)[i];
  __syncthreads();

#pragma unroll
  for (int m = 0; m < 2; ++m)
#pragma unroll
    for (int ct = 0; ct < 8; ++ct) acc[m][ct] = (f32x4)0.f;
#pragma unroll
  for (int kt = 0; kt < 4; ++kt)
#pragma unroll
    for (int ct = 0; ct < 8; ++ct) {
      int bidx = (kt * 4 + ks) * 128 + ct * 16 + fr;
      B8 bh, bl;
      bh.q = Blds[bidx];
      bl.q = Blds[bidx + 2048];
#pragma unroll
      for (int m = 0; m < 2; ++m) {
        acc[m][ct] = __builtin_amdgcn_mfma_f32_16x16x32_bf16(ah[m][kt].v, bh.v, acc[m][ct], 0, 0, 0);
        acc[m][ct] = __builtin_amdgcn_mfma_f32_16x16x32_bf16(ah[m][kt].v, bl.v, acc[m][ct], 0, 0, 0);
        acc[m][ct] = __builtin_amdgcn_mfma_f32_16x16x32_bf16(al[m][kt].v, bh.v, acc[m][ct], 0, 0, 0);
      }
    }
#pragma unroll
  for (int m = 0; m < 2; ++m)
#pragma unroll
    for (int ct = 0; ct < 8; ++ct) {
      int col = ct * 16 + fr;
#pragma unroll
      for (int r = 0; r < 4; ++r) {
        int row = rb0 + m * 16 + ks * 4 + r;
        if (row < M) V[(size_t)row * 128 + col] = acc[m][ct][r];
      }
    }
}

// ---------- GCN aggregate + relu + split to bf16 hi/lo ----------
// wave = 1 node; 4 lane-groups of 16 process neighbors mod-4 in parallel; 8 ch/lane (2xfloat4)
__global__ __launch_bounds__(256) void gcn_agg_split_k(
    const float* __restrict__ h, const int* __restrict__ csr_src,
    const float* __restrict__ csr_norm, const int* __restrict__ row_start,
    const float* __restrict__ dinv, const float* __restrict__ bias,
    unsigned* __restrict__ out_hi, unsigned* __restrict__ out_lo, int N) {
  int i = (blockIdx.x * blockDim.x + threadIdx.x) >> 6;
  int lane = threadIdx.x & 63;
  if (i >= N) return;
  const int g = lane >> 4, c8 = (lane & 15) * 8;
  float4 a0 = make_float4(0.f, 0.f, 0.f, 0.f);
  float4 a1 = make_float4(0.f, 0.f, 0.f, 0.f);
  int s0 = row_start[i], s1 = row_start[i + 1];
  if (g == 0) {  // self term
    float di = dinv[i];
    float sn = di * di;
    float4 v0 = *(const float4*)&h[(size_t)i * 128 + c8];
    float4 v1 = *(const float4*)&h[(size_t)i * 128 + c8 + 4];
    a0.x = v0.x * sn; a0.y = v0.y * sn; a0.z = v0.z * sn; a0.w = v0.w * sn;
    a1.x = v1.x * sn; a1.y = v1.y * sn; a1.z = v1.z * sn; a1.w = v1.w * sn;
  }
#pragma unroll 2
  for (int p = s0 + g; p < s1; p += 4) {
    int s = csr_src[p];
    float wgt = csr_norm[p];
    float4 h0 = *(const float4*)&h[(size_t)s * 128 + c8];
    float4 h1 = *(const float4*)&h[(size_t)s * 128 + c8 + 4];
    a0.x = fmaf(h0.x, wgt, a0.x); a0.y = fmaf(h0.y, wgt, a0.y);
    a0.z = fmaf(h0.z, wgt, a0.z); a0.w = fmaf(h0.w, wgt, a0.w);
    a1.x = fmaf(h1.x, wgt, a1.x); a1.y = fmaf(h1.y, wgt, a1.y);
    a1.z = fmaf(h1.z, wgt, a1.z); a1.w = fmaf(h1.w, wgt, a1.w);
  }
  // combine across 4 groups (lanes differing in bits 4,5)
#pragma unroll
  for (int off = 16; off < 64; off <<= 1) {
    a0.x += __shfl_xor(a0.x, off); a0.y += __shfl_xor(a0.y, off);
    a0.z += __shfl_xor(a0.z, off); a0.w += __shfl_xor(a0.w, off);
    a1.x += __shfl_xor(a1.x, off); a1.y += __shfl_xor(a1.y, off);
    a1.z += __shfl_xor(a1.z, off); a1.w += __shfl_xor(a1.w, off);
  }
  if (g == 0) {
    float4 b0 = *(const float4*)&bias[c8];
    float4 b1 = *(const float4*)&bias[c8 + 4];
    float v0 = fmaxf(a0.x + b0.x, 0.f), v1 = fmaxf(a0.y + b0.y, 0.f);
    float v2 = fmaxf(a0.z + b0.z, 0.f), v3 = fmaxf(a0.w + b0.w, 0.f);
    float v4 = fmaxf(a1.x + b1.x, 0.f), v5 = fmaxf(a1.y + b1.y, 0.f);
    float v6 = fmaxf(a1.z + b1.z, 0.f), v7 = fmaxf(a1.w + b1.w, 0.f);
    uint4 hh, ll;
    split2(v0, v1, hh.x, ll.x);
    split2(v2, v3, hh.y, ll.y);
    split2(v4, v5, hh.z, ll.z);
    split2(v6, v7, hh.w, ll.w);
    *(uint4*)&out_hi[(size_t)i * 64 + (lane & 15) * 4] = hh;
    *(uint4*)&out_lo[(size_t)i * 64 + (lane & 15) * 4] = ll;
  }
}

// ---------- EdgeConv: MFMA split-bf16, double-buffered kt pipeline, run-length max ----------
// 256 threads / 128-edge tiles, interleaved grid-stride (R3 occupancy sweet spot).
// be1 pre-folded into U. NO min-waves bound: VGPR must stay free (~260) — forcing 128
// spilled the pipeline buffers to scratch and doubled occupancy into L2 thrash (R7).
__global__ __launch_bounds__(256) void edgeconv_mfma(
    const float* __restrict__ U, const float* __restrict__ V,
    const int* __restrict__ csr_src, const int* __restrict__ csr_dst,
    const unsigned short* __restrict__ We2p, const float* __restrict__ be2,
    unsigned* __restrict__ agg, int E, int ntiles) {
  __shared__ uint4 Blds[4096];  // We2 hi (2048) + lo (2048)
  for (int i = threadIdx.x; i < 4096; i += 256) Blds[i] = ((const uint4*)We2p)[i];
  __syncthreads();
  const int w = threadIdx.x >> 6, lane = threadIdx.x & 63;
  const int ks = lane >> 4, fr = lane & 15;
  float b2[8];
#pragma unroll
  for (int ct = 0; ct < 8; ++ct) b2[ct] = be2[ct * 16 + fr];

  auto loadIdx = [&](int t, int (&d)[2], int (&s)[2]) {
    const int eb = t * 128 + w * 32;
#pragma unroll
    for (int m = 0; m < 2; ++m) {
      int el = ((fr >> 2) << 3) + (m << 2) + (fr & 3);
      int e = eb + el;
      int ee = (e < E) ? e : 0;
      d[m] = csr_dst[ee];
      s[m] = csr_src[ee];
    }
  };

  int tile = blockIdx.x;
  int dA[2] = {0, 0}, sA[2] = {0, 0};
  if (tile < ntiles) loadIdx(tile, dA, sA);

  for (; tile < ntiles; tile += gridDim.x) {
    const int eb = tile * 128 + w * 32;
    int dN[2] = {0, 0}, sN[2] = {0, 0};
    const int tn = tile + gridDim.x;
    if (tn < ntiles) loadIdx(tn, dN, sN);  // next-tile index prefetch

    f32x4 acc[2][8];
#pragma unroll
    for (int m = 0; m < 2; ++m)
#pragma unroll
      for (int ct = 0; ct < 8; ++ct) acc[m][ct] = (f32x4)0.f;

    // double-buffered raw U/V rows: [buf][m][half]
    float4 ru[2][2][2], rv[2][2][2];
    {
      const int k0 = ks * 8;
#pragma unroll
      for (int m = 0; m < 2; ++m) {
        const float4* up = (const float4*)&U[(size_t)dA[m] * 128 + k0];
        const float4* vp = (const float4*)&V[(size_t)sA[m] * 128 + k0];
        ru[0][m][0] = up[0]; ru[0][m][1] = up[1];
        rv[0][m][0] = vp[0]; rv[0][m][1] = vp[1];
      }
    }
#pragma unroll
    for (int kt = 0; kt < 4; ++kt) {
      const int cb = kt & 1, nb = cb ^ 1;
      if (kt < 3) {  // issue next kt's loads before compute
        const int k0n = (kt + 1) * 32 + ks * 8;
#pragma unroll
        for (int m = 0; m < 2; ++m) {
          const float4* up = (const float4*)&U[(size_t)dA[m] * 128 + k0n];
          const float4* vp = (const float4*)&V[(size_t)sA[m] * 128 + k0n];
          ru[nb][m][0] = up[0]; ru[nb][m][1] = up[1];
          rv[nb][m][0] = vp[0]; rv[nb][m][1] = vp[1];
        }
      }
      B8 ah[2], al[2];
#pragma unroll
      for (int m = 0; m < 2; ++m) {
        float4 u0 = ru[cb][m][0], u1 = ru[cb][m][1];
        float4 v0 = rv[cb][m][0], v1 = rv[cb][m][1];
        float s0 = fmaxf(u0.x + v0.x, 0.f);
        float s1 = fmaxf(u0.y + v0.y, 0.f);
        float s2 = fmaxf(u0.z + v0.z, 0.f);
        float s3 = fmaxf(u0.w + v0.w, 0.f);
        float s4 = fmaxf(u1.x + v1.x, 0.f);
        float s5 = fmaxf(u1.y + v1.y, 0.f);
        float s6 = fmaxf(u1.z + v1.z, 0.f);
        float s7 = fmaxf(u1.w + v1.w, 0.f);
        split2(s0, s1, ah[m].u[0], al[m].u[0]);
        split2(s2, s3, ah[m].u[1], al[m].u[1]);
        split2(s4, s5, ah[m].u[2], al[m].u[2]);
        split2(s6, s7, ah[m].u[3], al[m].u[3]);
      }
      __builtin_amdgcn_s_setprio(1);
#pragma unroll
      for (int ct = 0; ct < 8; ++ct) {
        int bidx = (kt * 4 + ks) * 128 + ct * 16 + fr;
        B8 bh, bl;
        bh.q = Blds[bidx];
        bl.q = Blds[bidx + 2048];
#pragma unroll
        for (int m = 0; m < 2; ++m) {
          acc[m][ct] = __builtin_amdgcn_mfma_f32_16x16x32_bf16(ah[m].v, bh.v, acc[m][ct], 0, 0, 0);
          acc[m][ct] = __builtin_amdgcn_mfma_f32_16x16x32_bf16(ah[m].v, bl.v, acc[m][ct], 0, 0, 0);
          acc[m][ct] = __builtin_amdgcn_mfma_f32_16x16x32_bf16(al[m].v, bh.v, acc[m][ct], 0, 0, 0);
        }
      }
      __builtin_amdgcn_s_setprio(0);
    }
    // epilogue: lane's 8 consecutive edges = (m,r) regs; run-length max, relu-first atomicMax
    const int ebase = eb + ks * 8;
    int prev = -1;
    float runv[8];
#pragma unroll
    for (int j = 0; j < 8; ++j) {
      int e = ebase + j;
      if (e < E) {
        int d = csr_dst[e];
        const int m = j >> 2, r = j & 3;
        if (d != prev) {
          if (prev >= 0) {
#pragma unroll
            for (int ct = 0; ct < 8; ++ct)
              atomicMax(&agg[(size_t)prev * 128 + ct * 16 + fr], __float_as_uint(runv[ct]));
          }
          prev = d;
#pragma unroll
          for (int ct = 0; ct < 8; ++ct) runv[ct] = fmaxf(acc[m][ct][r] + b2[ct], 0.f);
        } else {
#pragma unroll
          for (int ct = 0; ct < 8; ++ct)
            runv[ct] = fmaxf(runv[ct], fmaxf(acc[m][ct][r] + b2[ct], 0.f));
        }
      }
    }
    if (prev >= 0) {
#pragma unroll
      for (int ct = 0; ct < 8; ++ct)
        atomicMax(&agg[(size_t)prev * 128 + ct * 16 + fr], __float_as_uint(runv[ct]));
    }
    dA[0] = dN[0]; dA[1] = dN[1];
    sA[0] = sN[0]; sA[1] = sN[1];
  }
}

// ---------- graph boundaries (batch is sorted) ----------
__global__ void gbound_k(const int* __restrict__ batch, int* __restrict__ gstart, int N) {
  int g = threadIdx.x;
  if (g > NGRAPHS) return;
  if (g == NGRAPHS) { gstart[NGRAPHS] = N; return; }
  int lo = 0, hi = N;
  while (lo < hi) {
    int mid = (lo + hi) >> 1;
    if (batch[mid] < g) lo = mid + 1; else hi = mid;
  }
  gstart[g] = lo;
}

// ---------- segmented pooling: grid = NGRAPHS*8, one atomic pair per (block,channel) ----------
__global__ __launch_bounds__(256) void pool_seg_k(const float* __restrict__ x,
                                                  const int* __restrict__ gstart,
                                                  unsigned* __restrict__ gmax,
                                                  float* __restrict__ gsum) {
  int g = blockIdx.x >> 3, s = blockIdx.x & 7;
  int lb = gstart[g], ub = gstart[g + 1];
  long len = ub - lb;
  int i0 = lb + (int)((len * s) >> 3);
  int i1 = lb + (int)((len * (s + 1)) >> 3);
  int c = threadIdx.x & 127, h = threadIdx.x >> 7;
  float m = 0.f, sm = 0.f;
  for (int i = i0 + h; i < i1; i += 2) {
    float v = x[(size_t)i * 128 + c];
    m = fmaxf(m, v);
    sm += v;
  }
  if (i1 > i0) {
    atomicMax(&gmax[g * 128 + c], __float_as_uint(m));
    atomicAdd(&gsum[g * 128 + c], sm);
  }
}

__global__ void g0_k(const unsigned* __restrict__ gmax, const float* __restrict__ gsum,
                     const int* __restrict__ gstart, float* __restrict__ g0) {
  int t = blockIdx.x * blockDim.x + threadIdx.x;  // 64*256
  int g = t >> 8, c = t & 255;
  float o;
  if (c < 128) o = __uint_as_float(gmax[g * 128 + c]);
  else {
    float cnt = (float)(gstart[g + 1] - gstart[g]);
    o = gsum[g * 128 + (c - 128)] / fmaxf(cnt, 1.f);
  }
  g0[t] = o;
}

// ---------- head FC (relu) ----------
__global__ __launch_bounds__(256) void fc_k(const float* __restrict__ X,
                                            const float* __restrict__ W,
                                            const float* __restrict__ b,
                                            float* __restrict__ Y, int K, int N) {
  __shared__ float xs[256];
  int g = blockIdx.x, c = threadIdx.x;
  for (int k = c; k < K; k += blockDim.x) xs[k] = X[g * K + k];
  __syncthreads();
  float acc = b[c];
  for (int k = 0; k < K; k++) acc = fmaf(xs[k], W[(size_t)k * N + c], acc);
  Y[g * N + c] = fmaxf(acc, 0.f);
}

// ---------- launch ----------
extern "C" void kernel_launch(void* const* d_in, const int* in_sizes, int n_in,
                              void* d_out, int out_size, void* d_ws, size_t ws_size,
                              hipStream_t stream) {
  const float* nodes = (const float*)d_in[0];
  const int* cats = (const int*)d_in[1];
  const int* eidx = (const int*)d_in[2];
  const int* batch = (const int*)d_in[3];
  const float* emb = (const float*)d_in[4];
  const float* W1 = (const float*)d_in[5];
  const float* b1 = (const float*)d_in[6];
  const float* W2 = (const float*)d_in[7];
  const float* b2 = (const float*)d_in[8];
  const float* W3 = (const float*)d_in[9];
  const float* b3 = (const float*)d_in[10];
  const float* We1 = (const float*)d_in[11];
  const float* be1 = (const float*)d_in[12];
  const float* We2 = (const float*)d_in[13];
  const float* be2 = (const float*)d_in[14];
  const float* Wf1 = (const float*)d_in[15];
  const float* bf1 = (const float*)d_in[16];
  const float* Wf2 = (const float*)d_in[17];
  const float* bf2 = (const float*)d_in[18];
  float* out = (float*)d_out;

  const int N = in_sizes[0] / FEAT;
  const int E = in_sizes[2] / 2;
  const int Npad = ((N + 127) / 128) * 128;
  const int* src = eidx;
  const int* dst = eidx + E;

  char* w = (char*)d_ws;
  auto alloc = [&](size_t bytes) -> void* {
    void* p = (void*)w;
    w += (bytes + 255) & ~(size_t)255;
    return p;
  };
  unsigned* xh = (unsigned*)alloc((size_t)Npad * 32 * 4);   // [Npad x 64] bf16 pairs
  unsigned* xl = (unsigned*)alloc((size_t)Npad * 32 * 4);
  unsigned* ahb = (unsigned*)alloc((size_t)Npad * 64 * 4);  // [Npad x 128] bf16 pairs
  unsigned* alb = (unsigned*)alloc((size_t)Npad * 64 * 4);
  float* bufF = (float*)alloc((size_t)Npad * 128 * 4);      // gemm out / U
  float* bufV = (float*)alloc((size_t)Npad * 128 * 4);
  unsigned* agg = (unsigned*)alloc((size_t)N * 128 * 4);
  int* indeg = (int*)alloc((size_t)N * 4);
  int* rowst = (int*)alloc((size_t)(N + 1) * 4);
  int* cursor = (int*)alloc((size_t)N * 4);
  int* exclb = (int*)alloc((size_t)N * 4);
  int* bsum = (int*)alloc(128 * 4);
  float* dinv = (float*)alloc((size_t)N * 4);
  int* csr_src = (int*)alloc((size_t)E * 4);
  int* csr_dst = (int*)alloc((size_t)E * 4);
  float* csr_norm = (float*)alloc((size_t)E * 4);
  unsigned short* W1p = (unsigned short*)alloc(2 * 64 * 128 * 2);
  unsigned short* W2p = (unsigned short*)alloc(2 * 128 * 128 * 2);
  unsigned short* W3p = (unsigned short*)alloc(2 * 128 * 128 * 2);
  unsigned short* Wdp = (unsigned short*)alloc(2 * 128 * 128 * 2);
  unsigned short* Wvp = (unsigned short*)alloc(2 * 128 * 128 * 2);
  unsigned short* We2p = (unsigned short*)alloc(2 * 128 * 128 * 2);
  float* g0buf = (float*)alloc(NGRAPHS * 256 * 4);
  float* g1buf = (float*)alloc(NGRAPHS * 256 * 4);
  unsigned* gmax = (unsigned*)alloc(NGRAPHS * 128 * 4);
  float* gsum = (float*)alloc(NGRAPHS * 128 * 4);
  int* gstart = (int*)alloc((NGRAPHS + 1) * 4);
  if ((size_t)(w - (char*)d_ws) > ws_size) return;

  hipMemsetAsync(indeg, 0, (size_t)N * 4, stream);
  hipMemsetAsync(agg, 0, (size_t)N * 128 * 4, stream);
  hipMemsetAsync(gmax, 0, NGRAPHS * 128 * 4, stream);
  hipMemsetAsync(gsum, 0, NGRAPHS * 128 * 4, stream);

  const int TB = 256;
  int gE = (E + TB - 1) / TB;
  int gN = (N + TB - 1) / TB;
  int nb = (N + 1023) / 1024;

  hist_k<<<gE, TB, 0, stream>>>(dst, indeg, E);
  dinv_k<<<gN, TB, 0, stream>>>(indeg, dinv, N);
  scanA_k<<<nb, 1024, 0, stream>>>(indeg, exclb, bsum, N);
  scanB_k<<<1, 64, 0, stream>>>(bsum, nb);
  scanC_k<<<nb, 1024, 0, stream>>>(exclb, bsum, rowst, cursor, N, nb);
  fill_k<<<gE, TB, 0, stream>>>(src, dst, dinv, cursor, csr_src, csr_dst, csr_norm, E);
  gbound_k<<<1, 128, 0, stream>>>(batch, gstart, N);

  xcat_split_k<<<(N * 32 + TB - 1) / TB, TB, 0, stream>>>(nodes, cats, emb, xh, xl, N);

  pack_k<<<32, TB, 0, stream>>>(W1, nullptr, W1p, 64);
  pack_k<<<64, TB, 0, stream>>>(W2, nullptr, W2p, 128);
  pack_k<<<64, TB, 0, stream>>>(W3, nullptr, W3p, 128);
  pack_k<<<64, TB, 0, stream>>>(We1, We1 + 128 * 128, Wdp, 128);  // top - bot
  pack_k<<<64, TB, 0, stream>>>(We1 + 128 * 128, nullptr, Wvp, 128);
  pack_k<<<64, TB, 0, stream>>>(We2, nullptr, We2p, 128);

  const int gemmGrid = Npad / 128;
  const int waveGrid = (N * 64 + TB - 1) / TB;

  gemm_mfma<<<gemmGrid, TB, 0, stream>>>((unsigned short*)xh, (unsigned short*)xl, W1p, bufF, N, 64);
  gcn_agg_split_k<<<waveGrid, TB, 0, stream>>>(bufF, csr_src, csr_norm, rowst, dinv, b1, ahb, alb, N);
  gemm_mfma<<<gemmGrid, TB, 0, stream>>>((unsigned short*)ahb, (unsigned short*)alb, W2p, bufF, N, 128);
  gcn_agg_split_k<<<waveGrid, TB, 0, stream>>>(bufF, csr_src, csr_norm, rowst, dinv, b2, ahb, alb, N);
  gemm_mfma<<<gemmGrid, TB, 0, stream>>>((unsigned short*)ahb, (unsigned short*)alb, W3p, bufF, N, 128);
  gcn_agg_split_k<<<waveGrid, TB, 0, stream>>>(bufF, csr_src, csr_norm, rowst, dinv, b3, ahb, alb, N);

  // EdgeConv precompute: U = x3 @ (We1_top - We1_bot) + be1, V = x3 @ We1_bot (fused)
  gemm_dual_mfma<<<gemmGrid, TB, 0, stream>>>((unsigned short*)ahb, (unsigned short*)alb,
                                              Wdp, Wvp, be1, bufF, bufV, N);

  const int ntiles = (E + 127) / 128;
  edgeconv_mfma<<<2048, TB, 0, stream>>>(bufF, bufV, csr_src, csr_dst, We2p, be2, agg, E, ntiles);

  pool_seg_k<<<NGRAPHS * 8, TB, 0, stream>>>((const float*)agg, gstart, gmax, gsum);
  g0_k<<<NGRAPHS, TB, 0, stream>>>(gmax, gsum, gstart, g0buf);
  fc_k<<<NGRAPHS, 256, 0, stream>>>(g0buf, Wf1, bf1, g1buf, 256, 256);
  fc_k<<<NGRAPHS, 256, 0, stream>>>(g1buf, Wf2, bf2, out, 256, 256);
}

// Round 9
// 708.018 us; speedup vs baseline: 1.2622x; 1.0102x over previous
//
#include <hip/hip_runtime.h>

#define FEAT 32
#define EMB 32
#define HID 128
#define NGRAPHS 64

typedef short short8 __attribute__((ext_vector_type(8)));
typedef float f32x4 __attribute__((ext_vector_type(4)));

union B8 { uint4 q; unsigned u[4]; short8 v; };

// round-to-nearest-even bf16, returned as f32 bits with low16 zeroed
__device__ __forceinline__ unsigned bf16_rne_bits(float f) {
  unsigned u = __float_as_uint(f);
  unsigned r = u + 0x7FFFu + ((u >> 16) & 1u);
  return r & 0xFFFF0000u;
}
// split a,b (f32) into packed bf16 hi-pair and lo-pair (elem0 low16, elem1 high16)
__device__ __forceinline__ void split2(float a, float b, unsigned& hp, unsigned& lp) {
  unsigned ha = bf16_rne_bits(a), hb = bf16_rne_bits(b);
  float la = a - __uint_as_float(ha), lb = b - __uint_as_float(hb);
  unsigned laa = bf16_rne_bits(la), lbb = bf16_rne_bits(lb);
  hp = (ha >> 16) | (hb & 0xFFFF0000u);
  lp = (laa >> 16) | (lbb & 0xFFFF0000u);
}

// ---------- CSR build ----------
__global__ void hist_k(const int* __restrict__ dst, int* __restrict__ indeg, int E) {
  int e = blockIdx.x * blockDim.x + threadIdx.x;
  if (e < E) atomicAdd(&indeg[dst[e]], 1);
}

__global__ void dinv_k(const int* __restrict__ indeg, float* __restrict__ dinv, int N) {
  int i = blockIdx.x * blockDim.x + threadIdx.x;
  if (i < N) dinv[i] = rsqrtf((float)indeg[i] + 1.0f);  // +1 self loop
}

// ---------- parallel 3-phase exclusive scan of indeg ----------
__global__ __launch_bounds__(1024) void scanA_k(const int* __restrict__ indeg,
                                                int* __restrict__ excl,
                                                int* __restrict__ bsum, int N) {
  __shared__ int wsum[16];
  int i = blockIdx.x * 1024 + threadIdx.x;
  const int lane = threadIdx.x & 63;
  const int wid = threadIdx.x >> 6;
  int val = (i < N) ? indeg[i] : 0;
  int x = val;
#pragma unroll
  for (int off = 1; off < 64; off <<= 1) {
    int y = __shfl_up(x, off, 64);
    if (lane >= off) x += y;
  }
  if (lane == 63) wsum[wid] = x;
  __syncthreads();
  if (wid == 0) {
    int s = (lane < 16) ? wsum[lane] : 0;
#pragma unroll
    for (int off = 1; off < 16; off <<= 1) {
      int y = __shfl_up(s, off, 64);
      if (lane >= off) s += y;
    }
    if (lane < 16) wsum[lane] = s;
  }
  __syncthreads();
  int ex = x - val + ((wid > 0) ? wsum[wid - 1] : 0);
  if (i < N) excl[i] = ex;
  if (threadIdx.x == 0) bsum[blockIdx.x] = wsum[15];
}

__global__ void scanB_k(int* __restrict__ bsum, int nb) {  // nb <= 64, one wave
  int lane = threadIdx.x;
  int v = (lane < nb) ? bsum[lane] : 0;
  int x = v;
#pragma unroll
  for (int off = 1; off < 64; off <<= 1) {
    int y = __shfl_up(x, off, 64);
    if (lane >= off) x += y;
  }
  if (lane < nb) bsum[lane] = x - v;
  if (lane == nb - 1) bsum[nb] = x;  // grand total
}

__global__ __launch_bounds__(1024) void scanC_k(const int* __restrict__ excl,
                                                const int* __restrict__ bsum,
                                                int* __restrict__ row_start,
                                                int* __restrict__ cursor, int N, int nb) {
  int i = blockIdx.x * 1024 + threadIdx.x;
  if (i < N) {
    int v = excl[i] + bsum[blockIdx.x];
    row_start[i] = v;
    cursor[i] = v;
  }
  if (i == 0) row_start[N] = bsum[nb];
}

__global__ void fill_k(const int* __restrict__ src, const int* __restrict__ dst,
                       const float* __restrict__ dinv, int* __restrict__ cursor,
                       int* __restrict__ csr_src, int* __restrict__ csr_dst,
                       float* __restrict__ csr_norm, int E) {
  int e = blockIdx.x * blockDim.x + threadIdx.x;
  if (e >= E) return;
  int d = dst[e], s = src[e];
  int p = atomicAdd(&cursor[d], 1);
  csr_src[p] = s;
  csr_dst[p] = d;
  csr_norm[p] = dinv[s] * dinv[d];
}

// ---------- weight packing into MFMA-fragment layout (hi then lo) ----------
// out[((kt*4+ks)*128 + c)*8 + j] = bf16(W[kt*32+ks*8+j][c]); lo at +K*128
__global__ void pack_k(const float* __restrict__ WA, const float* __restrict__ WB,
                       unsigned short* __restrict__ out, int K) {
  int t = blockIdx.x * blockDim.x + threadIdx.x;
  if (t >= K * 128) return;
  int k = t >> 7, c = t & 127;
  float v = WA[k * 128 + c];
  if (WB) v -= WB[k * 128 + c];
  unsigned hb = bf16_rne_bits(v);
  float lo = v - __uint_as_float(hb);
  unsigned lb = bf16_rne_bits(lo);
  int kt = k >> 5, ks = (k >> 3) & 3, j = k & 7;
  int idx = ((kt * 4 + ks) * 128 + c) * 8 + j;
  out[idx] = (unsigned short)(hb >> 16);
  out[K * 128 + idx] = (unsigned short)(lb >> 16);
}

// ---------- feature assembly: split concat(nodes, emb[cat]) to bf16 hi/lo ----------
__global__ void xcat_split_k(const float* __restrict__ nodes, const int* __restrict__ cats,
                             const float* __restrict__ emb, unsigned* __restrict__ xh,
                             unsigned* __restrict__ xl, int N) {
  int t = blockIdx.x * blockDim.x + threadIdx.x;  // N*32, 2 channels each
  if (t >= N * 32) return;
  int i = t >> 5, p = t & 31;
  float2 v = (p < 16) ? ((const float2*)nodes)[(size_t)i * 16 + p]
                      : ((const float2*)emb)[(size_t)cats[i] * 16 + (p - 16)];
  unsigned hp, lp;
  split2(v.x, v.y, hp, lp);
  xh[(size_t)i * 32 + p] = hp;
  xl[(size_t)i * 32 + p] = lp;
}

// ---------- split-bf16 MFMA GEMM: C[M x 128] = A @ B ; A row-major K, B packed ----------
__global__ __launch_bounds__(256) void gemm_mfma(const unsigned short* __restrict__ Ah,
                                                 const unsigned short* __restrict__ Al,
                                                 const unsigned short* __restrict__ Bp,
                                                 float* __restrict__ C, int M, int K) {
  __shared__ uint4 Blds[4096];  // 64KB max (K=128); K=64 uses 2048
  const int nq = K * 32;        // uint4 count (hi+lo)
  for (int i = threadIdx.x; i < nq; i += 256) Blds[i] = ((const uint4*)Bp)[i];
  __syncthreads();
  const int w = threadIdx.x >> 6, lane = threadIdx.x & 63;
  const int ks = lane >> 4, fr = lane & 15;
  const int rb0 = blockIdx.x * 128 + w * 32;
  const int loBase = K * 16;  // uint4 offset of lo half
  f32x4 acc[2][8];
#pragma unroll
  for (int m = 0; m < 2; ++m)
#pragma unroll
    for (int ct = 0; ct < 8; ++ct) acc[m][ct] = (f32x4)0.f;

  const int nkt = K >> 5;
  for (int kt = 0; kt < nkt; ++kt) {
    B8 ah[2], al[2];
#pragma unroll
    for (int m = 0; m < 2; ++m) {
      size_t off = (size_t)(rb0 + m * 16 + fr) * K + kt * 32 + ks * 8;
      ah[m].q = *(const uint4*)(Ah + off);
      al[m].q = *(const uint4*)(Al + off);
    }
#pragma unroll
    for (int ct = 0; ct < 8; ++ct) {
      int bidx = (kt * 4 + ks) * 128 + ct * 16 + fr;
      B8 bh, bl;
      bh.q = Blds[bidx];
      bl.q = Blds[bidx + loBase];
#pragma unroll
      for (int m = 0; m < 2; ++m) {
        acc[m][ct] = __builtin_amdgcn_mfma_f32_16x16x32_bf16(ah[m].v, bh.v, acc[m][ct], 0, 0, 0);
        acc[m][ct] = __builtin_amdgcn_mfma_f32_16x16x32_bf16(ah[m].v, bl.v, acc[m][ct], 0, 0, 0);
        acc[m][ct] = __builtin_amdgcn_mfma_f32_16x16x32_bf16(al[m].v, bh.v, acc[m][ct], 0, 0, 0);
      }
    }
  }
#pragma unroll
  for (int m = 0; m < 2; ++m)
#pragma unroll
    for (int ct = 0; ct < 8; ++ct) {
      int col = ct * 16 + fr;
#pragma unroll
      for (int r = 0; r < 4; ++r) {
        int row = rb0 + m * 16 + ks * 4 + r;
        if (row < M) C[(size_t)row * 128 + col] = acc[m][ct][r];
      }
    }
}

// ---------- dual GEMM (K=128): U = A@B1 + bias1, V = A@B2 ; A-frags loaded once ----------
__global__ __launch_bounds__(256) void gemm_dual_mfma(const unsigned short* __restrict__ Ah,
                                                      const unsigned short* __restrict__ Al,
                                                      const unsigned short* __restrict__ Bp1,
                                                      const unsigned short* __restrict__ Bp2,
                                                      const float* __restrict__ bias1,
                                                      float* __restrict__ U,
                                                      float* __restrict__ V, int M) {
  __shared__ uint4 Blds[4096];
  for (int i = threadIdx.x; i < 4096; i += 256) Blds[i] = ((const uint4*)Bp1)[i];
  const int w = threadIdx.x >> 6, lane = threadIdx.x & 63;
  const int ks = lane >> 4, fr = lane & 15;
  const int rb0 = blockIdx.x * 128 + w * 32;
  B8 ah[2][4], al[2][4];
#pragma unroll
  for (int m = 0; m < 2; ++m)
#pragma unroll
    for (int kt = 0; kt < 4; ++kt) {
      size_t off = (size_t)(rb0 + m * 16 + fr) * 128 + kt * 32 + ks * 8;
      ah[m][kt].q = *(const uint4*)(Ah + off);
      al[m][kt].q = *(const uint4*)(Al + off);
    }
  __syncthreads();

  f32x4 acc[2][8];
#pragma unroll
  for (int m = 0; m < 2; ++m)
#pragma unroll
    for (int ct = 0; ct < 8; ++ct) acc[m][ct] = (f32x4)0.f;
#pragma unroll
  for (int kt = 0; kt < 4; ++kt)
#pragma unroll
    for (int ct = 0; ct < 8; ++ct) {
      int bidx = (kt * 4 + ks) * 128 + ct * 16 + fr;
      B8 bh, bl;
      bh.q = Blds[bidx];
      bl.q = Blds[bidx + 2048];
#pragma unroll
      for (int m = 0; m < 2; ++m) {
        acc[m][ct] = __builtin_amdgcn_mfma_f32_16x16x32_bf16(ah[m][kt].v, bh.v, acc[m][ct], 0, 0, 0);
        acc[m][ct] = __builtin_amdgcn_mfma_f32_16x16x32_bf16(ah[m][kt].v, bl.v, acc[m][ct], 0, 0, 0);
        acc[m][ct] = __builtin_amdgcn_mfma_f32_16x16x32_bf16(al[m][kt].v, bh.v, acc[m][ct], 0, 0, 0);
      }
    }
#pragma unroll
  for (int m = 0; m < 2; ++m)
#pragma unroll
    for (int ct = 0; ct < 8; ++ct) {
      int col = ct * 16 + fr;
      float bv = bias1[col];
#pragma unroll
      for (int r = 0; r < 4; ++r) {
        int row = rb0 + m * 16 + ks * 4 + r;
        if (row < M) U[(size_t)row * 128 + col] = acc[m][ct][r] + bv;
      }
    }

  __syncthreads();  // all pass-1 LDS reads done
  for (int i = threadIdx.x; i < 4096; i += 256) Blds[i] = ((const uint4*)Bp2)[i];
  __syncthreads();

#pragma unroll
  for (int m = 0; m < 2; ++m)
#pragma unroll
    for (int ct = 0; ct < 8; ++ct) acc[m][ct] = (f32x4)0.f;
#pragma unroll
  for (int kt = 0; kt < 4; ++kt)
#pragma unroll
    for (int ct = 0; ct < 8; ++ct) {
      int bidx = (kt * 4 + ks) * 128 + ct * 16 + fr;
      B8 bh, bl;
      bh.q = Blds[bidx];
      bl.q = Blds[bidx + 2048];
#pragma unroll
      for (int m = 0; m < 2; ++m) {
        acc[m][ct] = __builtin_amdgcn_mfma_f32_16x16x32_bf16(ah[m][kt].v, bh.v, acc[m][ct], 0, 0, 0);
        acc[m][ct] = __builtin_amdgcn_mfma_f32_16x16x32_bf16(ah[m][kt].v, bl.v, acc[m][ct], 0, 0, 0);
        acc[m][ct] = __builtin_amdgcn_mfma_f32_16x16x32_bf16(al[m][kt].v, bh.v, acc[m][ct], 0, 0, 0);
      }
    }
#pragma unroll
  for (int m = 0; m < 2; ++m)
#pragma unroll
    for (int ct = 0; ct < 8; ++ct) {
      int col = ct * 16 + fr;
#pragma unroll
      for (int r = 0; r < 4; ++r) {
        int row = rb0 + m * 16 + ks * 4 + r;
        if (row < M) V[(size_t)row * 128 + col] = acc[m][ct][r];
      }
    }
}

// ---------- GCN aggregate + relu + split to bf16 hi/lo ----------
// wave = 1 node; 4 lane-groups of 16 process neighbors mod-4; 8 ch/lane (2xfloat4).
// 4-deep explicit unroll: 4 independent row streams per group (tail rows get weight 0 -> exact).
__global__ __launch_bounds__(256) void gcn_agg_split_k(
    const float* __restrict__ h, const int* __restrict__ csr_src,
    const float* __restrict__ csr_norm, const int* __restrict__ row_start,
    const float* __restrict__ dinv, const float* __restrict__ bias,
    unsigned* __restrict__ out_hi, unsigned* __restrict__ out_lo, int N) {
  int i = (blockIdx.x * blockDim.x + threadIdx.x) >> 6;
  int lane = threadIdx.x & 63;
  if (i >= N) return;
  const int g = lane >> 4, c8 = (lane & 15) * 8;
  float4 a0 = make_float4(0.f, 0.f, 0.f, 0.f);
  float4 a1 = make_float4(0.f, 0.f, 0.f, 0.f);
  int s0 = row_start[i], s1 = row_start[i + 1];
  if (g == 0) {  // self term
    float di = dinv[i];
    float sn = di * di;
    float4 v0 = *(const float4*)&h[(size_t)i * 128 + c8];
    float4 v1 = *(const float4*)&h[(size_t)i * 128 + c8 + 4];
    a0.x = v0.x * sn; a0.y = v0.y * sn; a0.z = v0.z * sn; a0.w = v0.w * sn;
    a1.x = v1.x * sn; a1.y = v1.y * sn; a1.z = v1.z * sn; a1.w = v1.w * sn;
  }
  for (int p = s0 + g; p < s1; p += 16) {
    int idx[4]; float wt[4];
#pragma unroll
    for (int j = 0; j < 4; ++j) {
      int q = p + 4 * j;
      if (q < s1) { idx[j] = csr_src[q]; wt[j] = csr_norm[q]; }
      else        { idx[j] = 0;          wt[j] = 0.f; }
    }
#pragma unroll
    for (int j = 0; j < 4; ++j) {
      const float4* hp = (const float4*)&h[(size_t)idx[j] * 128 + c8];
      float4 h0 = hp[0], h1 = hp[1];
      float wgt = wt[j];
      a0.x = fmaf(h0.x, wgt, a0.x); a0.y = fmaf(h0.y, wgt, a0.y);
      a0.z = fmaf(h0.z, wgt, a0.z); a0.w = fmaf(h0.w, wgt, a0.w);
      a1.x = fmaf(h1.x, wgt, a1.x); a1.y = fmaf(h1.y, wgt, a1.y);
      a1.z = fmaf(h1.z, wgt, a1.z); a1.w = fmaf(h1.w, wgt, a1.w);
    }
  }
  // combine across 4 groups (lanes differing in bits 4,5)
#pragma unroll
  for (int off = 16; off < 64; off <<= 1) {
    a0.x += __shfl_xor(a0.x, off); a0.y += __shfl_xor(a0.y, off);
    a0.z += __shfl_xor(a0.z, off); a0.w += __shfl_xor(a0.w, off);
    a1.x += __shfl_xor(a1.x, off); a1.y += __shfl_xor(a1.y, off);
    a1.z += __shfl_xor(a1.z, off); a1.w += __shfl_xor(a1.w, off);
  }
  if (g == 0) {
    float4 b0 = *(const float4*)&bias[c8];
    float4 b1 = *(const float4*)&bias[c8 + 4];
    float v0 = fmaxf(a0.x + b0.x, 0.f), v1 = fmaxf(a0.y + b0.y, 0.f);
    float v2 = fmaxf(a0.z + b0.z, 0.f), v3 = fmaxf(a0.w + b0.w, 0.f);
    float v4 = fmaxf(a1.x + b1.x, 0.f), v5 = fmaxf(a1.y + b1.y, 0.f);
    float v6 = fmaxf(a1.z + b1.z, 0.f), v7 = fmaxf(a1.w + b1.w, 0.f);
    uint4 hh, ll;
    split2(v0, v1, hh.x, ll.x);
    split2(v2, v3, hh.y, ll.y);
    split2(v4, v5, hh.z, ll.z);
    split2(v6, v7, hh.w, ll.w);
    *(uint4*)&out_hi[(size_t)i * 64 + (lane & 15) * 4] = hh;
    *(uint4*)&out_lo[(size_t)i * 64 + (lane & 15) * 4] = ll;
  }
}

// ---------- EdgeConv: MFMA split-bf16, cross-tile software pipeline, run-length max ----------
// 256 threads / 128-edge tiles, interleaved grid-stride (occupancy sweet spot: 2 blocks/CU,
// VGPR free up to 256 — forcing lower spills, R7). kt=3 slot preloads NEXT tile's kt0 rows.
__global__ __launch_bounds__(256) void edgeconv_mfma(
    const float* __restrict__ U, const float* __restrict__ V,
    const int* __restrict__ csr_src, const int* __restrict__ csr_dst,
    const unsigned short* __restrict__ We2p, const float* __restrict__ be2,
    unsigned* __restrict__ agg, int E, int ntiles) {
  __shared__ uint4 Blds[4096];  // We2 hi (2048) + lo (2048)
  for (int i = threadIdx.x; i < 4096; i += 256) Blds[i] = ((const uint4*)We2p)[i];
  __syncthreads();
  const int w = threadIdx.x >> 6, lane = threadIdx.x & 63;
  const int ks = lane >> 4, fr = lane & 15;
  float b2[8];
#pragma unroll
  for (int ct = 0; ct < 8; ++ct) b2[ct] = be2[ct * 16 + fr];

  auto loadIdx = [&](int t, int (&d)[2], int (&s)[2]) {
    const int eb = t * 128 + w * 32;
#pragma unroll
    for (int m = 0; m < 2; ++m) {
      int el = ((fr >> 2) << 3) + (m << 2) + (fr & 3);
      int e = eb + el;
      int ee = (e < E) ? e : 0;
      d[m] = csr_dst[ee];
      s[m] = csr_src[ee];
    }
  };

  int tile = blockIdx.x;
  int dA[2] = {0, 0}, sA[2] = {0, 0};
  // pipeline state: buf0 holds current tile's kt0 rows on loop entry
  float4 ru[2][2][2], rv[2][2][2];
  if (tile < ntiles) {
    loadIdx(tile, dA, sA);
    const int k0 = ks * 8;
#pragma unroll
    for (int m = 0; m < 2; ++m) {
      const float4* up = (const float4*)&U[(size_t)dA[m] * 128 + k0];
      const float4* vp = (const float4*)&V[(size_t)sA[m] * 128 + k0];
      ru[0][m][0] = up[0]; ru[0][m][1] = up[1];
      rv[0][m][0] = vp[0]; rv[0][m][1] = vp[1];
    }
  }

  for (; tile < ntiles; tile += gridDim.x) {
    const int eb = tile * 128 + w * 32;
    int dN[2] = {0, 0}, sN[2] = {0, 0};
    const int tn = tile + gridDim.x;
    if (tn < ntiles) loadIdx(tn, dN, sN);  // next-tile index prefetch

    f32x4 acc[2][8];
#pragma unroll
    for (int m = 0; m < 2; ++m)
#pragma unroll
      for (int ct = 0; ct < 8; ++ct) acc[m][ct] = (f32x4)0.f;

#pragma unroll
    for (int kt = 0; kt < 4; ++kt) {
      const int cb = kt & 1, nb = cb ^ 1;
      if (kt < 3) {  // issue next kt's loads before compute
        const int k0n = (kt + 1) * 32 + ks * 8;
#pragma unroll
        for (int m = 0; m < 2; ++m) {
          const float4* up = (const float4*)&U[(size_t)dA[m] * 128 + k0n];
          const float4* vp = (const float4*)&V[(size_t)sA[m] * 128 + k0n];
          ru[nb][m][0] = up[0]; ru[nb][m][1] = up[1];
          rv[nb][m][0] = vp[0]; rv[nb][m][1] = vp[1];
        }
      } else {  // kt==3, nb==0: preload NEXT tile's kt0 rows -> hides tile-start latency
        const int k0n = ks * 8;
#pragma unroll
        for (int m = 0; m < 2; ++m) {
          const float4* up = (const float4*)&U[(size_t)dN[m] * 128 + k0n];
          const float4* vp = (const float4*)&V[(size_t)sN[m] * 128 + k0n];
          ru[0][m][0] = up[0]; ru[0][m][1] = up[1];
          rv[0][m][0] = vp[0]; rv[0][m][1] = vp[1];
        }
      }
      B8 ah[2], al[2];
#pragma unroll
      for (int m = 0; m < 2; ++m) {
        float4 u0 = ru[cb][m][0], u1 = ru[cb][m][1];
        float4 v0 = rv[cb][m][0], v1 = rv[cb][m][1];
        float s0 = fmaxf(u0.x + v0.x, 0.f);
        float s1 = fmaxf(u0.y + v0.y, 0.f);
        float s2 = fmaxf(u0.z + v0.z, 0.f);
        float s3 = fmaxf(u0.w + v0.w, 0.f);
        float s4 = fmaxf(u1.x + v1.x, 0.f);
        float s5 = fmaxf(u1.y + v1.y, 0.f);
        float s6 = fmaxf(u1.z + v1.z, 0.f);
        float s7 = fmaxf(u1.w + v1.w, 0.f);
        split2(s0, s1, ah[m].u[0], al[m].u[0]);
        split2(s2, s3, ah[m].u[1], al[m].u[1]);
        split2(s4, s5, ah[m].u[2], al[m].u[2]);
        split2(s6, s7, ah[m].u[3], al[m].u[3]);
      }
      __builtin_amdgcn_s_setprio(1);
#pragma unroll
      for (int ct = 0; ct < 8; ++ct) {
        int bidx = (kt * 4 + ks) * 128 + ct * 16 + fr;
        B8 bh, bl;
        bh.q = Blds[bidx];
        bl.q = Blds[bidx + 2048];
#pragma unroll
        for (int m = 0; m < 2; ++m) {
          acc[m][ct] = __builtin_amdgcn_mfma_f32_16x16x32_bf16(ah[m].v, bh.v, acc[m][ct], 0, 0, 0);
          acc[m][ct] = __builtin_amdgcn_mfma_f32_16x16x32_bf16(ah[m].v, bl.v, acc[m][ct], 0, 0, 0);
          acc[m][ct] = __builtin_amdgcn_mfma_f32_16x16x32_bf16(al[m].v, bh.v, acc[m][ct], 0, 0, 0);
        }
      }
      __builtin_amdgcn_s_setprio(0);
    }
    // epilogue: lane's 8 consecutive edges = (m,r) regs; run-length max, relu-first atomicMax
    const int ebase = eb + ks * 8;
    int prev = -1;
    float runv[8];
#pragma unroll
    for (int j = 0; j < 8; ++j) {
      int e = ebase + j;
      if (e < E) {
        int d = csr_dst[e];
        const int m = j >> 2, r = j & 3;
        if (d != prev) {
          if (prev >= 0) {
#pragma unroll
            for (int ct = 0; ct < 8; ++ct)
              atomicMax(&agg[(size_t)prev * 128 + ct * 16 + fr], __float_as_uint(runv[ct]));
          }
          prev = d;
#pragma unroll
          for (int ct = 0; ct < 8; ++ct) runv[ct] = fmaxf(acc[m][ct][r] + b2[ct], 0.f);
        } else {
#pragma unroll
          for (int ct = 0; ct < 8; ++ct)
            runv[ct] = fmaxf(runv[ct], fmaxf(acc[m][ct][r] + b2[ct], 0.f));
        }
      }
    }
    if (prev >= 0) {
#pragma unroll
      for (int ct = 0; ct < 8; ++ct)
        atomicMax(&agg[(size_t)prev * 128 + ct * 16 + fr], __float_as_uint(runv[ct]));
    }
    dA[0] = dN[0]; dA[1] = dN[1];
    sA[0] = sN[0]; sA[1] = sN[1];
  }
}

// ---------- graph boundaries (batch is sorted) ----------
__global__ void gbound_k(const int* __restrict__ batch, int* __restrict__ gstart, int N) {
  int g = threadIdx.x;
  if (g > NGRAPHS) return;
  if (g == NGRAPHS) { gstart[NGRAPHS] = N; return; }
  int lo = 0, hi = N;
  while (lo < hi) {
    int mid = (lo + hi) >> 1;
    if (batch[mid] < g) lo = mid + 1; else hi = mid;
  }
  gstart[g] = lo;
}

// ---------- segmented pooling: grid = NGRAPHS*8, one atomic pair per (block,channel) ----------
__global__ __launch_bounds__(256) void pool_seg_k(const float* __restrict__ x,
                                                  const int* __restrict__ gstart,
                                                  unsigned* __restrict__ gmax,
                                                  float* __restrict__ gsum) {
  int g = blockIdx.x >> 3, s = blockIdx.x & 7;
  int lb = gstart[g], ub = gstart[g + 1];
  long len = ub - lb;
  int i0 = lb + (int)((len * s) >> 3);
  int i1 = lb + (int)((len * (s + 1)) >> 3);
  int c = threadIdx.x & 127, h = threadIdx.x >> 7;
  float m = 0.f, sm = 0.f;
  for (int i = i0 + h; i < i1; i += 2) {
    float v = x[(size_t)i * 128 + c];
    m = fmaxf(m, v);
    sm += v;
  }
  if (i1 > i0) {
    atomicMax(&gmax[g * 128 + c], __float_as_uint(m));
    atomicAdd(&gsum[g * 128 + c], sm);
  }
}

__global__ void g0_k(const unsigned* __restrict__ gmax, const float* __restrict__ gsum,
                     const int* __restrict__ gstart, float* __restrict__ g0) {
  int t = blockIdx.x * blockDim.x + threadIdx.x;  // 64*256
  int g = t >> 8, c = t & 255;
  float o;
  if (c < 128) o = __uint_as_float(gmax[g * 128 + c]);
  else {
    float cnt = (float)(gstart[g + 1] - gstart[g]);
    o = gsum[g * 128 + (c - 128)] / fmaxf(cnt, 1.f);
  }
  g0[t] = o;
}

// ---------- head FC (relu) ----------
__global__ __launch_bounds__(256) void fc_k(const float* __restrict__ X,
                                            const float* __restrict__ W,
                                            const float* __restrict__ b,
                                            float* __restrict__ Y, int K, int N) {
  __shared__ float xs[256];
  int g = blockIdx.x, c = threadIdx.x;
  for (int k = c; k < K; k += blockDim.x) xs[k] = X[g * K + k];
  __syncthreads();
  float acc = b[c];
  for (int k = 0; k < K; k++) acc = fmaf(xs[k], W[(size_t)k * N + c], acc);
  Y[g * N + c] = fmaxf(acc, 0.f);
}

// ---------- launch ----------
extern "C" void kernel_launch(void* const* d_in, const int* in_sizes, int n_in,
                              void* d_out, int out_size, void* d_ws, size_t ws_size,
                              hipStream_t stream) {
  const float* nodes = (const float*)d_in[0];
  const int* cats = (const int*)d_in[1];
  const int* eidx = (const int*)d_in[2];
  const int* batch = (const int*)d_in[3];
  const float* emb = (const float*)d_in[4];
  const float* W1 = (const float*)d_in[5];
  const float* b1 = (const float*)d_in[6];
  const float* W2 = (const float*)d_in[7];
  const float* b2 = (const float*)d_in[8];
  const float* W3 = (const float*)d_in[9];
  const float* b3 = (const float*)d_in[10];
  const float* We1 = (const float*)d_in[11];
  const float* be1 = (const float*)d_in[12];
  const float* We2 = (const float*)d_in[13];
  const float* be2 = (const float*)d_in[14];
  const float* Wf1 = (const float*)d_in[15];
  const float* bf1 = (const float*)d_in[16];
  const float* Wf2 = (const float*)d_in[17];
  const float* bf2 = (const float*)d_in[18];
  float* out = (float*)d_out;

  const int N = in_sizes[0] / FEAT;
  const int E = in_sizes[2] / 2;
  const int Npad = ((N + 127) / 128) * 128;
  const int* src = eidx;
  const int* dst = eidx + E;

  char* w = (char*)d_ws;
  auto alloc = [&](size_t bytes) -> void* {
    void* p = (void*)w;
    w += (bytes + 255) & ~(size_t)255;
    return p;
  };
  unsigned* xh = (unsigned*)alloc((size_t)Npad * 32 * 4);   // [Npad x 64] bf16 pairs
  unsigned* xl = (unsigned*)alloc((size_t)Npad * 32 * 4);
  unsigned* ahb = (unsigned*)alloc((size_t)Npad * 64 * 4);  // [Npad x 128] bf16 pairs
  unsigned* alb = (unsigned*)alloc((size_t)Npad * 64 * 4);
  float* bufF = (float*)alloc((size_t)Npad * 128 * 4);      // gemm out / U
  float* bufV = (float*)alloc((size_t)Npad * 128 * 4);
  unsigned* agg = (unsigned*)alloc((size_t)N * 128 * 4);
  int* indeg = (int*)alloc((size_t)N * 4);
  int* rowst = (int*)alloc((size_t)(N + 1) * 4);
  int* cursor = (int*)alloc((size_t)N * 4);
  int* exclb = (int*)alloc((size_t)N * 4);
  int* bsum = (int*)alloc(128 * 4);
  float* dinv = (float*)alloc((size_t)N * 4);
  int* csr_src = (int*)alloc((size_t)E * 4);
  int* csr_dst = (int*)alloc((size_t)E * 4);
  float* csr_norm = (float*)alloc((size_t)E * 4);
  unsigned short* W1p = (unsigned short*)alloc(2 * 64 * 128 * 2);
  unsigned short* W2p = (unsigned short*)alloc(2 * 128 * 128 * 2);
  unsigned short* W3p = (unsigned short*)alloc(2 * 128 * 128 * 2);
  unsigned short* Wdp = (unsigned short*)alloc(2 * 128 * 128 * 2);
  unsigned short* Wvp = (unsigned short*)alloc(2 * 128 * 128 * 2);
  unsigned short* We2p = (unsigned short*)alloc(2 * 128 * 128 * 2);
  float* g0buf = (float*)alloc(NGRAPHS * 256 * 4);
  float* g1buf = (float*)alloc(NGRAPHS * 256 * 4);
  unsigned* gmax = (unsigned*)alloc(NGRAPHS * 128 * 4);
  float* gsum = (float*)alloc(NGRAPHS * 128 * 4);
  int* gstart = (int*)alloc((NGRAPHS + 1) * 4);
  if ((size_t)(w - (char*)d_ws) > ws_size) return;

  hipMemsetAsync(indeg, 0, (size_t)N * 4, stream);
  hipMemsetAsync(agg, 0, (size_t)N * 128 * 4, stream);
  hipMemsetAsync(gmax, 0, NGRAPHS * 128 * 4, stream);
  hipMemsetAsync(gsum, 0, NGRAPHS * 128 * 4, stream);

  const int TB = 256;
  int gE = (E + TB - 1) / TB;
  int gN = (N + TB - 1) / TB;
  int nb = (N + 1023) / 1024;

  hist_k<<<gE, TB, 0, stream>>>(dst, indeg, E);
  dinv_k<<<gN, TB, 0, stream>>>(indeg, dinv, N);
  scanA_k<<<nb, 1024, 0, stream>>>(indeg, exclb, bsum, N);
  scanB_k<<<1, 64, 0, stream>>>(bsum, nb);
  scanC_k<<<nb, 1024, 0, stream>>>(exclb, bsum, rowst, cursor, N, nb);
  fill_k<<<gE, TB, 0, stream>>>(src, dst, dinv, cursor, csr_src, csr_dst, csr_norm, E);
  gbound_k<<<1, 128, 0, stream>>>(batch, gstart, N);

  xcat_split_k<<<(N * 32 + TB - 1) / TB, TB, 0, stream>>>(nodes, cats, emb, xh, xl, N);

  pack_k<<<32, TB, 0, stream>>>(W1, nullptr, W1p, 64);
  pack_k<<<64, TB, 0, stream>>>(W2, nullptr, W2p, 128);
  pack_k<<<64, TB, 0, stream>>>(W3, nullptr, W3p, 128);
  pack_k<<<64, TB, 0, stream>>>(We1, We1 + 128 * 128, Wdp, 128);  // top - bot
  pack_k<<<64, TB, 0, stream>>>(We1 + 128 * 128, nullptr, Wvp, 128);
  pack_k<<<64, TB, 0, stream>>>(We2, nullptr, We2p, 128);

  const int gemmGrid = Npad / 128;
  const int waveGrid = (N * 64 + TB - 1) / TB;

  gemm_mfma<<<gemmGrid, TB, 0, stream>>>((unsigned short*)xh, (unsigned short*)xl, W1p, bufF, N, 64);
  gcn_agg_split_k<<<waveGrid, TB, 0, stream>>>(bufF, csr_src, csr_norm, rowst, dinv, b1, ahb, alb, N);
  gemm_mfma<<<gemmGrid, TB, 0, stream>>>((unsigned short*)ahb, (unsigned short*)alb, W2p, bufF, N, 128);
  gcn_agg_split_k<<<waveGrid, TB, 0, stream>>>(bufF, csr_src, csr_norm, rowst, dinv, b2, ahb, alb, N);
  gemm_mfma<<<gemmGrid, TB, 0, stream>>>((unsigned short*)ahb, (unsigned short*)alb, W3p, bufF, N, 128);
  gcn_agg_split_k<<<waveGrid, TB, 0, stream>>>(bufF, csr_src, csr_norm, rowst, dinv, b3, ahb, alb, N);

  // EdgeConv precompute: U = x3 @ (We1_top - We1_bot) + be1, V = x3 @ We1_bot (fused)
  gemm_dual_mfma<<<gemmGrid, TB, 0, stream>>>((unsigned short*)ahb, (unsigned short*)alb,
                                              Wdp, Wvp, be1, bufF, bufV, N);

  const int ntiles = (E + 127) / 128;
  edgeconv_mfma<<<2048, TB, 0, stream>>>(bufF, bufV, csr_src, csr_dst, We2p, be2, agg, E, ntiles);

  pool_seg_k<<<NGRAPHS * 8, TB, 0, stream>>>((const float*)agg, gstart, gmax, gsum);
  g0_k<<<NGRAPHS, TB, 0, stream>>>(gmax, gsum, gstart, g0buf);
  fc_k<<<NGRAPHS, 256, 0, stream>>>(g0buf, Wf1, bf1, g1buf, 256, 256);
  fc_k<<<NGRAPHS, 256, 0, stream>>>(g1buf, Wf2, bf2, out, 256, 256);
}

// Round 10
// 662.740 us; speedup vs baseline: 1.3484x; 1.0683x over previous
//
#include <hip/hip_runtime.h>

#define FEAT 32
#define EMB 32
#define HID 128
#define NGRAPHS 64

typedef short short8 __attribute__((ext_vector_type(8)));
typedef float f32x4 __attribute__((ext_vector_type(4)));

union B8 { uint4 q; unsigned u[4]; short8 v; };

// round-to-nearest-even bf16, returned as f32 bits with low16 zeroed
__device__ __forceinline__ unsigned bf16_rne_bits(float f) {
  unsigned u = __float_as_uint(f);
  unsigned r = u + 0x7FFFu + ((u >> 16) & 1u);
  return r & 0xFFFF0000u;
}
// split a,b (f32) into packed bf16 hi-pair and lo-pair (elem0 low16, elem1 high16)
__device__ __forceinline__ void split2(float a, float b, unsigned& hp, unsigned& lp) {
  unsigned ha = bf16_rne_bits(a), hb = bf16_rne_bits(b);
  float la = a - __uint_as_float(ha), lb = b - __uint_as_float(hb);
  unsigned laa = bf16_rne_bits(la), lbb = bf16_rne_bits(lb);
  hp = (ha >> 16) | (hb & 0xFFFF0000u);
  lp = (laa >> 16) | (lbb & 0xFFFF0000u);
}

// ---------- CSR build ----------
__global__ void hist_k(const int* __restrict__ dst, int* __restrict__ indeg, int E) {
  int e = blockIdx.x * blockDim.x + threadIdx.x;
  if (e < E) atomicAdd(&indeg[dst[e]], 1);
}

// ---------- parallel 3-phase exclusive scan of indeg (also computes dinv) ----------
__global__ __launch_bounds__(1024) void scanA_k(const int* __restrict__ indeg,
                                                int* __restrict__ excl,
                                                int* __restrict__ bsum,
                                                float* __restrict__ dinv, int N) {
  __shared__ int wsum[16];
  int i = blockIdx.x * 1024 + threadIdx.x;
  const int lane = threadIdx.x & 63;
  const int wid = threadIdx.x >> 6;
  int val = (i < N) ? indeg[i] : 0;
  if (i < N) dinv[i] = rsqrtf((float)val + 1.0f);  // +1 self loop
  int x = val;
#pragma unroll
  for (int off = 1; off < 64; off <<= 1) {
    int y = __shfl_up(x, off, 64);
    if (lane >= off) x += y;
  }
  if (lane == 63) wsum[wid] = x;
  __syncthreads();
  if (wid == 0) {
    int s = (lane < 16) ? wsum[lane] : 0;
#pragma unroll
    for (int off = 1; off < 16; off <<= 1) {
      int y = __shfl_up(s, off, 64);
      if (lane >= off) s += y;
    }
    if (lane < 16) wsum[lane] = s;
  }
  __syncthreads();
  int ex = x - val + ((wid > 0) ? wsum[wid - 1] : 0);
  if (i < N) excl[i] = ex;
  if (threadIdx.x == 0) bsum[blockIdx.x] = wsum[15];
}

__global__ void scanB_k(int* __restrict__ bsum, int nb) {  // nb <= 64, one wave
  int lane = threadIdx.x;
  int v = (lane < nb) ? bsum[lane] : 0;
  int x = v;
#pragma unroll
  for (int off = 1; off < 64; off <<= 1) {
    int y = __shfl_up(x, off, 64);
    if (lane >= off) x += y;
  }
  if (lane < nb) bsum[lane] = x - v;
  if (lane == nb - 1) bsum[nb] = x;  // grand total
}

__global__ __launch_bounds__(1024) void scanC_k(const int* __restrict__ excl,
                                                const int* __restrict__ bsum,
                                                int* __restrict__ row_start,
                                                int* __restrict__ cursor, int N, int nb) {
  int i = blockIdx.x * 1024 + threadIdx.x;
  if (i < N) {
    int v = excl[i] + bsum[blockIdx.x];
    row_start[i] = v;
    cursor[i] = v;
  }
  if (i == 0) row_start[N] = bsum[nb];
}

__global__ void fill_k(const int* __restrict__ src, const int* __restrict__ dst,
                       const float* __restrict__ dinv, int* __restrict__ cursor,
                       int* __restrict__ csr_src, int* __restrict__ csr_dst,
                       float* __restrict__ csr_norm, int E) {
  int e = blockIdx.x * blockDim.x + threadIdx.x;
  if (e >= E) return;
  int d = dst[e], s = src[e];
  int p = atomicAdd(&cursor[d], 1);
  csr_src[p] = s;
  csr_dst[p] = d;
  csr_norm[p] = dinv[s] * dinv[d];
}

// ---------- ALL weight packs in one launch ----------
// layout: out[((kt*4+ks)*128 + c)*8 + j] = bf16(W[kt*32+ks*8+j][c]); lo at +K*128
__global__ void pack_all_k(const float* __restrict__ W1, const float* __restrict__ W2,
                           const float* __restrict__ W3, const float* __restrict__ We1,
                           const float* __restrict__ We2,
                           unsigned short* __restrict__ W1p, unsigned short* __restrict__ W2p,
                           unsigned short* __restrict__ W3p, unsigned short* __restrict__ Wdp,
                           unsigned short* __restrict__ Wvp, unsigned short* __restrict__ We2p) {
  int b = blockIdx.x;  // 32 + 5*64 = 352 blocks
  const float* WA;
  const float* WB = nullptr;
  unsigned short* out;
  int K, t0;
  if (b < 32)       { WA = W1;            out = W1p;  K = 64;  t0 = b; }
  else if (b < 96)  { WA = W2;            out = W2p;  K = 128; t0 = b - 32; }
  else if (b < 160) { WA = W3;            out = W3p;  K = 128; t0 = b - 96; }
  else if (b < 224) { WA = We1; WB = We1 + 16384; out = Wdp; K = 128; t0 = b - 160; }
  else if (b < 288) { WA = We1 + 16384;   out = Wvp;  K = 128; t0 = b - 224; }
  else              { WA = We2;           out = We2p; K = 128; t0 = b - 288; }
  int t = t0 * 256 + threadIdx.x;
  if (t >= K * 128) return;
  int k = t >> 7, c = t & 127;
  float v = WA[k * 128 + c];
  if (WB) v -= WB[k * 128 + c];
  unsigned hb = bf16_rne_bits(v);
  float lo = v - __uint_as_float(hb);
  unsigned lb = bf16_rne_bits(lo);
  int kt = k >> 5, ks = (k >> 3) & 3, j = k & 7;
  int idx = ((kt * 4 + ks) * 128 + c) * 8 + j;
  out[idx] = (unsigned short)(hb >> 16);
  out[K * 128 + idx] = (unsigned short)(lb >> 16);
}

// ---------- feature assembly: split concat(nodes, emb[cat]) to bf16 hi/lo ----------
__global__ void xcat_split_k(const float* __restrict__ nodes, const int* __restrict__ cats,
                             const float* __restrict__ emb, unsigned* __restrict__ xh,
                             unsigned* __restrict__ xl, int N) {
  int t = blockIdx.x * blockDim.x + threadIdx.x;  // N*32, 2 channels each
  if (t >= N * 32) return;
  int i = t >> 5, p = t & 31;
  float2 v = (p < 16) ? ((const float2*)nodes)[(size_t)i * 16 + p]
                      : ((const float2*)emb)[(size_t)cats[i] * 16 + (p - 16)];
  unsigned hp, lp;
  split2(v.x, v.y, hp, lp);
  xh[(size_t)i * 32 + p] = hp;
  xl[(size_t)i * 32 + p] = lp;
}

// ---------- layer-1 aggregation BEFORE GEMM: gathers 64-ch split rows (256 B/row) ----------
// wave = node; 2 groups of 32 lanes process neighbors mod-2, 4-deep unroll;
// lane owns channel pair (2p, 2p+1) via one u32 from xh + one from xl.
__global__ __launch_bounds__(256) void gcn_aggpre_k(
    const unsigned* __restrict__ xh, const unsigned* __restrict__ xl,
    const int* __restrict__ csr_src, const float* __restrict__ csr_norm,
    const int* __restrict__ row_start, const float* __restrict__ dinv,
    unsigned* __restrict__ out_hi, unsigned* __restrict__ out_lo, int N) {
  int i = (blockIdx.x * blockDim.x + threadIdx.x) >> 6;
  int lane = threadIdx.x & 63;
  if (i >= N) return;
  const int g = lane >> 5, cp = lane & 31;
  float a0 = 0.f, a1 = 0.f;
  int s0 = row_start[i], s1 = row_start[i + 1];
  if (g == 0) {  // self term
    float di = dinv[i];
    float sn = di * di;
    unsigned uh = xh[(size_t)i * 32 + cp], ul = xl[(size_t)i * 32 + cp];
    float x0 = __uint_as_float(uh << 16) + __uint_as_float(ul << 16);
    float x1 = __uint_as_float(uh & 0xFFFF0000u) + __uint_as_float(ul & 0xFFFF0000u);
    a0 = x0 * sn;
    a1 = x1 * sn;
  }
  for (int p = s0 + g; p < s1; p += 8) {
    int idx[4]; float wt[4];
#pragma unroll
    for (int j = 0; j < 4; ++j) {
      int q = p + 2 * j;
      if (q < s1) { idx[j] = csr_src[q]; wt[j] = csr_norm[q]; }
      else        { idx[j] = 0;          wt[j] = 0.f; }
    }
#pragma unroll
    for (int j = 0; j < 4; ++j) {
      unsigned uh = xh[(size_t)idx[j] * 32 + cp], ul = xl[(size_t)idx[j] * 32 + cp];
      float x0 = __uint_as_float(uh << 16) + __uint_as_float(ul << 16);
      float x1 = __uint_as_float(uh & 0xFFFF0000u) + __uint_as_float(ul & 0xFFFF0000u);
      a0 = fmaf(x0, wt[j], a0);
      a1 = fmaf(x1, wt[j], a1);
    }
  }
  a0 += __shfl_xor(a0, 32);
  a1 += __shfl_xor(a1, 32);
  if (g == 0) {
    unsigned hp, lp;
    split2(a0, a1, hp, lp);
    out_hi[(size_t)i * 32 + cp] = hp;
    out_lo[(size_t)i * 32 + cp] = lp;
  }
}

// ---------- bias + relu + split (layer-1 GEMM epilogue) ----------
__global__ void brs_k(const float* __restrict__ h, const float* __restrict__ bias,
                      unsigned* __restrict__ out_hi, unsigned* __restrict__ out_lo, int N) {
  int t = blockIdx.x * blockDim.x + threadIdx.x;  // N*64 channel pairs
  if (t >= N * 64) return;
  int i = t >> 6, p = t & 63;
  float2 v = ((const float2*)h)[(size_t)i * 64 + p];
  float2 bv = ((const float2*)bias)[p];
  float a0 = fmaxf(v.x + bv.x, 0.f), a1 = fmaxf(v.y + bv.y, 0.f);
  unsigned hp, lp;
  split2(a0, a1, hp, lp);
  out_hi[(size_t)i * 64 + p] = hp;
  out_lo[(size_t)i * 64 + p] = lp;
}

// ---------- split-bf16 MFMA GEMM: C[M x 128] = A @ B ; A row-major K, B packed ----------
__global__ __launch_bounds__(256) void gemm_mfma(const unsigned short* __restrict__ Ah,
                                                 const unsigned short* __restrict__ Al,
                                                 const unsigned short* __restrict__ Bp,
                                                 float* __restrict__ C, int M, int K) {
  __shared__ uint4 Blds[4096];  // 64KB max (K=128); K=64 uses 2048
  const int nq = K * 32;        // uint4 count (hi+lo)
  for (int i = threadIdx.x; i < nq; i += 256) Blds[i] = ((const uint4*)Bp)[i];
  __syncthreads();
  const int w = threadIdx.x >> 6, lane = threadIdx.x & 63;
  const int ks = lane >> 4, fr = lane & 15;
  const int rb0 = blockIdx.x * 128 + w * 32;
  const int loBase = K * 16;  // uint4 offset of lo half
  f32x4 acc[2][8];
#pragma unroll
  for (int m = 0; m < 2; ++m)
#pragma unroll
    for (int ct = 0; ct < 8; ++ct) acc[m][ct] = (f32x4)0.f;

  const int nkt = K >> 5;
  for (int kt = 0; kt < nkt; ++kt) {
    B8 ah[2], al[2];
#pragma unroll
    for (int m = 0; m < 2; ++m) {
      size_t off = (size_t)(rb0 + m * 16 + fr) * K + kt * 32 + ks * 8;
      ah[m].q = *(const uint4*)(Ah + off);
      al[m].q = *(const uint4*)(Al + off);
    }
#pragma unroll
    for (int ct = 0; ct < 8; ++ct) {
      int bidx = (kt * 4 + ks) * 128 + ct * 16 + fr;
      B8 bh, bl;
      bh.q = Blds[bidx];
      bl.q = Blds[bidx + loBase];
#pragma unroll
      for (int m = 0; m < 2; ++m) {
        acc[m][ct] = __builtin_amdgcn_mfma_f32_16x16x32_bf16(ah[m].v, bh.v, acc[m][ct], 0, 0, 0);
        acc[m][ct] = __builtin_amdgcn_mfma_f32_16x16x32_bf16(ah[m].v, bl.v, acc[m][ct], 0, 0, 0);
        acc[m][ct] = __builtin_amdgcn_mfma_f32_16x16x32_bf16(al[m].v, bh.v, acc[m][ct], 0, 0, 0);
      }
    }
  }
#pragma unroll
  for (int m = 0; m < 2; ++m)
#pragma unroll
    for (int ct = 0; ct < 8; ++ct) {
      int col = ct * 16 + fr;
#pragma unroll
      for (int r = 0; r < 4; ++r) {
        int row = rb0 + m * 16 + ks * 4 + r;
        if (row < M) C[(size_t)row * 128 + col] = acc[m][ct][r];
      }
    }
}

// ---------- dual GEMM (K=128): U = A@B1 + bias1, V = A@B2 ; A-frags loaded once ----------
__global__ __launch_bounds__(256) void gemm_dual_mfma(const unsigned short* __restrict__ Ah,
                                                      const unsigned short* __restrict__ Al,
                                                      const unsigned short* __restrict__ Bp1,
                                                      const unsigned short* __restrict__ Bp2,
                                                      const float* __restrict__ bias1,
                                                      float* __restrict__ U,
                                                      float* __restrict__ V, int M) {
  __shared__ uint4 Blds[4096];
  for (int i = threadIdx.x; i < 4096; i += 256) Blds[i] = ((const uint4*)Bp1)[i];
  const int w = threadIdx.x >> 6, lane = threadIdx.x & 63;
  const int ks = lane >> 4, fr = lane & 15;
  const int rb0 = blockIdx.x * 128 + w * 32;
  B8 ah[2][4], al[2][4];
#pragma unroll
  for (int m = 0; m < 2; ++m)
#pragma unroll
    for (int kt = 0; kt < 4; ++kt) {
      size_t off = (size_t)(rb0 + m * 16 + fr) * 128 + kt * 32 + ks * 8;
      ah[m][kt].q = *(const uint4*)(Ah + off);
      al[m][kt].q = *(const uint4*)(Al + off);
    }
  __syncthreads();

  f32x4 acc[2][8];
#pragma unroll
  for (int m = 0; m < 2; ++m)
#pragma unroll
    for (int ct = 0; ct < 8; ++ct) acc[m][ct] = (f32x4)0.f;
#pragma unroll
  for (int kt = 0; kt < 4; ++kt)
#pragma unroll
    for (int ct = 0; ct < 8; ++ct) {
      int bidx = (kt * 4 + ks) * 128 + ct * 16 + fr;
      B8 bh, bl;
      bh.q = Blds[bidx];
      bl.q = Blds[bidx + 2048];
#pragma unroll
      for (int m = 0; m < 2; ++m) {
        acc[m][ct] = __builtin_amdgcn_mfma_f32_16x16x32_bf16(ah[m][kt].v, bh.v, acc[m][ct], 0, 0, 0);
        acc[m][ct] = __builtin_amdgcn_mfma_f32_16x16x32_bf16(ah[m][kt].v, bl.v, acc[m][ct], 0, 0, 0);
        acc[m][ct] = __builtin_amdgcn_mfma_f32_16x16x32_bf16(al[m][kt].v, bh.v, acc[m][ct], 0, 0, 0);
      }
    }
#pragma unroll
  for (int m = 0; m < 2; ++m)
#pragma unroll
    for (int ct = 0; ct < 8; ++ct) {
      int col = ct * 16 + fr;
      float bv = bias1[col];
#pragma unroll
      for (int r = 0; r < 4; ++r) {
        int row = rb0 + m * 16 + ks * 4 + r;
        if (row < M) U[(size_t)row * 128 + col] = acc[m][ct][r] + bv;
      }
    }

  __syncthreads();  // all pass-1 LDS reads done
  for (int i = threadIdx.x; i < 4096; i += 256) Blds[i] = ((const uint4*)Bp2)[i];
  __syncthreads();

#pragma unroll
  for (int m = 0; m < 2; ++m)
#pragma unroll
    for (int ct = 0; ct < 8; ++ct) acc[m][ct] = (f32x4)0.f;
#pragma unroll
  for (int kt = 0; kt < 4; ++kt)
#pragma unroll
    for (int ct = 0; ct < 8; ++ct) {
      int bidx = (kt * 4 + ks) * 128 + ct * 16 + fr;
      B8 bh, bl;
      bh.q = Blds[bidx];
      bl.q = Blds[bidx + 2048];
#pragma unroll
      for (int m = 0; m < 2; ++m) {
        acc[m][ct] = __builtin_amdgcn_mfma_f32_16x16x32_bf16(ah[m][kt].v, bh.v, acc[m][ct], 0, 0, 0);
        acc[m][ct] = __builtin_amdgcn_mfma_f32_16x16x32_bf16(ah[m][kt].v, bl.v, acc[m][ct], 0, 0, 0);
        acc[m][ct] = __builtin_amdgcn_mfma_f32_16x16x32_bf16(al[m][kt].v, bh.v, acc[m][ct], 0, 0, 0);
      }
    }
#pragma unroll
  for (int m = 0; m < 2; ++m)
#pragma unroll
    for (int ct = 0; ct < 8; ++ct) {
      int col = ct * 16 + fr;
#pragma unroll
      for (int r = 0; r < 4; ++r) {
        int row = rb0 + m * 16 + ks * 4 + r;
        if (row < M) V[(size_t)row * 128 + col] = acc[m][ct][r];
      }
    }
}

// ---------- GCN aggregate + relu + split to bf16 hi/lo (layers 2,3) ----------
// wave = 1 node; 4 lane-groups of 16 process neighbors mod-4; 8 ch/lane (2xfloat4).
__global__ __launch_bounds__(256) void gcn_agg_split_k(
    const float* __restrict__ h, const int* __restrict__ csr_src,
    const float* __restrict__ csr_norm, const int* __restrict__ row_start,
    const float* __restrict__ dinv, const float* __restrict__ bias,
    unsigned* __restrict__ out_hi, unsigned* __restrict__ out_lo, int N) {
  int i = (blockIdx.x * blockDim.x + threadIdx.x) >> 6;
  int lane = threadIdx.x & 63;
  if (i >= N) return;
  const int g = lane >> 4, c8 = (lane & 15) * 8;
  float4 a0 = make_float4(0.f, 0.f, 0.f, 0.f);
  float4 a1 = make_float4(0.f, 0.f, 0.f, 0.f);
  int s0 = row_start[i], s1 = row_start[i + 1];
  if (g == 0) {  // self term
    float di = dinv[i];
    float sn = di * di;
    float4 v0 = *(const float4*)&h[(size_t)i * 128 + c8];
    float4 v1 = *(const float4*)&h[(size_t)i * 128 + c8 + 4];
    a0.x = v0.x * sn; a0.y = v0.y * sn; a0.z = v0.z * sn; a0.w = v0.w * sn;
    a1.x = v1.x * sn; a1.y = v1.y * sn; a1.z = v1.z * sn; a1.w = v1.w * sn;
  }
  for (int p = s0 + g; p < s1; p += 16) {
    int idx[4]; float wt[4];
#pragma unroll
    for (int j = 0; j < 4; ++j) {
      int q = p + 4 * j;
      if (q < s1) { idx[j] = csr_src[q]; wt[j] = csr_norm[q]; }
      else        { idx[j] = 0;          wt[j] = 0.f; }
    }
#pragma unroll
    for (int j = 0; j < 4; ++j) {
      const float4* hp = (const float4*)&h[(size_t)idx[j] * 128 + c8];
      float4 h0 = hp[0], h1 = hp[1];
      float wgt = wt[j];
      a0.x = fmaf(h0.x, wgt, a0.x); a0.y = fmaf(h0.y, wgt, a0.y);
      a0.z = fmaf(h0.z, wgt, a0.z); a0.w = fmaf(h0.w, wgt, a0.w);
      a1.x = fmaf(h1.x, wgt, a1.x); a1.y = fmaf(h1.y, wgt, a1.y);
      a1.z = fmaf(h1.z, wgt, a1.z); a1.w = fmaf(h1.w, wgt, a1.w);
    }
  }
  // combine across 4 groups (lanes differing in bits 4,5)
#pragma unroll
  for (int off = 16; off < 64; off <<= 1) {
    a0.x += __shfl_xor(a0.x, off); a0.y += __shfl_xor(a0.y, off);
    a0.z += __shfl_xor(a0.z, off); a0.w += __shfl_xor(a0.w, off);
    a1.x += __shfl_xor(a1.x, off); a1.y += __shfl_xor(a1.y, off);
    a1.z += __shfl_xor(a1.z, off); a1.w += __shfl_xor(a1.w, off);
  }
  if (g == 0) {
    float4 b0 = *(const float4*)&bias[c8];
    float4 b1 = *(const float4*)&bias[c8 + 4];
    float v0 = fmaxf(a0.x + b0.x, 0.f), v1 = fmaxf(a0.y + b0.y, 0.f);
    float v2 = fmaxf(a0.z + b0.z, 0.f), v3 = fmaxf(a0.w + b0.w, 0.f);
    float v4 = fmaxf(a1.x + b1.x, 0.f), v5 = fmaxf(a1.y + b1.y, 0.f);
    float v6 = fmaxf(a1.z + b1.z, 0.f), v7 = fmaxf(a1.w + b1.w, 0.f);
    uint4 hh, ll;
    split2(v0, v1, hh.x, ll.x);
    split2(v2, v3, hh.y, ll.y);
    split2(v4, v5, hh.z, ll.z);
    split2(v6, v7, hh.w, ll.w);
    *(uint4*)&out_hi[(size_t)i * 64 + (lane & 15) * 4] = hh;
    *(uint4*)&out_lo[(size_t)i * 64 + (lane & 15) * 4] = ll;
  }
}

// ---------- EdgeConv: MFMA split-bf16, cross-tile software pipeline, run-length max ----------
// 256 threads / 128-edge tiles, interleaved grid-stride (occupancy sweet spot: 2 blocks/CU,
// VGPR free up to 256 — forcing lower spills, R7). kt=3 slot preloads NEXT tile's kt0 rows.
__global__ __launch_bounds__(256) void edgeconv_mfma(
    const float* __restrict__ U, const float* __restrict__ V,
    const int* __restrict__ csr_src, const int* __restrict__ csr_dst,
    const unsigned short* __restrict__ We2p, const float* __restrict__ be2,
    unsigned* __restrict__ agg, int E, int ntiles) {
  __shared__ uint4 Blds[4096];  // We2 hi (2048) + lo (2048)
  for (int i = threadIdx.x; i < 4096; i += 256) Blds[i] = ((const uint4*)We2p)[i];
  __syncthreads();
  const int w = threadIdx.x >> 6, lane = threadIdx.x & 63;
  const int ks = lane >> 4, fr = lane & 15;
  float b2[8];
#pragma unroll
  for (int ct = 0; ct < 8; ++ct) b2[ct] = be2[ct * 16 + fr];

  auto loadIdx = [&](int t, int (&d)[2], int (&s)[2]) {
    const int eb = t * 128 + w * 32;
#pragma unroll
    for (int m = 0; m < 2; ++m) {
      int el = ((fr >> 2) << 3) + (m << 2) + (fr & 3);
      int e = eb + el;
      int ee = (e < E) ? e : 0;
      d[m] = csr_dst[ee];
      s[m] = csr_src[ee];
    }
  };

  int tile = blockIdx.x;
  int dA[2] = {0, 0}, sA[2] = {0, 0};
  // pipeline state: buf0 holds current tile's kt0 rows on loop entry
  float4 ru[2][2][2], rv[2][2][2];
  if (tile < ntiles) {
    loadIdx(tile, dA, sA);
    const int k0 = ks * 8;
#pragma unroll
    for (int m = 0; m < 2; ++m) {
      const float4* up = (const float4*)&U[(size_t)dA[m] * 128 + k0];
      const float4* vp = (const float4*)&V[(size_t)sA[m] * 128 + k0];
      ru[0][m][0] = up[0]; ru[0][m][1] = up[1];
      rv[0][m][0] = vp[0]; rv[0][m][1] = vp[1];
    }
  }

  for (; tile < ntiles; tile += gridDim.x) {
    const int eb = tile * 128 + w * 32;
    int dN[2] = {0, 0}, sN[2] = {0, 0};
    const int tn = tile + gridDim.x;
    if (tn < ntiles) loadIdx(tn, dN, sN);  // next-tile index prefetch

    f32x4 acc[2][8];
#pragma unroll
    for (int m = 0; m < 2; ++m)
#pragma unroll
      for (int ct = 0; ct < 8; ++ct) acc[m][ct] = (f32x4)0.f;

#pragma unroll
    for (int kt = 0; kt < 4; ++kt) {
      const int cb = kt & 1, nb = cb ^ 1;
      if (kt < 3) {  // issue next kt's loads before compute
        const int k0n = (kt + 1) * 32 + ks * 8;
#pragma unroll
        for (int m = 0; m < 2; ++m) {
          const float4* up = (const float4*)&U[(size_t)dA[m] * 128 + k0n];
          const float4* vp = (const float4*)&V[(size_t)sA[m] * 128 + k0n];
          ru[nb][m][0] = up[0]; ru[nb][m][1] = up[1];
          rv[nb][m][0] = vp[0]; rv[nb][m][1] = vp[1];
        }
      } else {  // kt==3, nb==0: preload NEXT tile's kt0 rows -> hides tile-start latency
        const int k0n = ks * 8;
#pragma unroll
        for (int m = 0; m < 2; ++m) {
          const float4* up = (const float4*)&U[(size_t)dN[m] * 128 + k0n];
          const float4* vp = (const float4*)&V[(size_t)sN[m] * 128 + k0n];
          ru[0][m][0] = up[0]; ru[0][m][1] = up[1];
          rv[0][m][0] = vp[0]; rv[0][m][1] = vp[1];
        }
      }
      B8 ah[2], al[2];
#pragma unroll
      for (int m = 0; m < 2; ++m) {
        float4 u0 = ru[cb][m][0], u1 = ru[cb][m][1];
        float4 v0 = rv[cb][m][0], v1 = rv[cb][m][1];
        float s0 = fmaxf(u0.x + v0.x, 0.f);
        float s1 = fmaxf(u0.y + v0.y, 0.f);
        float s2 = fmaxf(u0.z + v0.z, 0.f);
        float s3 = fmaxf(u0.w + v0.w, 0.f);
        float s4 = fmaxf(u1.x + v1.x, 0.f);
        float s5 = fmaxf(u1.y + v1.y, 0.f);
        float s6 = fmaxf(u1.z + v1.z, 0.f);
        float s7 = fmaxf(u1.w + v1.w, 0.f);
        split2(s0, s1, ah[m].u[0], al[m].u[0]);
        split2(s2, s3, ah[m].u[1], al[m].u[1]);
        split2(s4, s5, ah[m].u[2], al[m].u[2]);
        split2(s6, s7, ah[m].u[3], al[m].u[3]);
      }
      __builtin_amdgcn_s_setprio(1);
#pragma unroll
      for (int ct = 0; ct < 8; ++ct) {
        int bidx = (kt * 4 + ks) * 128 + ct * 16 + fr;
        B8 bh, bl;
        bh.q = Blds[bidx];
        bl.q = Blds[bidx + 2048];
#pragma unroll
        for (int m = 0; m < 2; ++m) {
          acc[m][ct] = __builtin_amdgcn_mfma_f32_16x16x32_bf16(ah[m].v, bh.v, acc[m][ct], 0, 0, 0);
          acc[m][ct] = __builtin_amdgcn_mfma_f32_16x16x32_bf16(ah[m].v, bl.v, acc[m][ct], 0, 0, 0);
          acc[m][ct] = __builtin_amdgcn_mfma_f32_16x16x32_bf16(al[m].v, bh.v, acc[m][ct], 0, 0, 0);
        }
      }
      __builtin_amdgcn_s_setprio(0);
    }
    // epilogue: lane's 8 consecutive edges = (m,r) regs; run-length max, relu-first atomicMax
    const int ebase = eb + ks * 8;
    int prev = -1;
    float runv[8];
#pragma unroll
    for (int j = 0; j < 8; ++j) {
      int e = ebase + j;
      if (e < E) {
        int d = csr_dst[e];
        const int m = j >> 2, r = j & 3;
        if (d != prev) {
          if (prev >= 0) {
#pragma unroll
            for (int ct = 0; ct < 8; ++ct)
              atomicMax(&agg[(size_t)prev * 128 + ct * 16 + fr], __float_as_uint(runv[ct]));
          }
          prev = d;
#pragma unroll
          for (int ct = 0; ct < 8; ++ct) runv[ct] = fmaxf(acc[m][ct][r] + b2[ct], 0.f);
        } else {
#pragma unroll
          for (int ct = 0; ct < 8; ++ct)
            runv[ct] = fmaxf(runv[ct], fmaxf(acc[m][ct][r] + b2[ct], 0.f));
        }
      }
    }
    if (prev >= 0) {
#pragma unroll
      for (int ct = 0; ct < 8; ++ct)
        atomicMax(&agg[(size_t)prev * 128 + ct * 16 + fr], __float_as_uint(runv[ct]));
    }
    dA[0] = dN[0]; dA[1] = dN[1];
    sA[0] = sN[0]; sA[1] = sN[1];
  }
}

// ---------- graph boundaries (batch is sorted) ----------
__global__ void gbound_k(const int* __restrict__ batch, int* __restrict__ gstart, int N) {
  int g = threadIdx.x;
  if (g > NGRAPHS) return;
  if (g == NGRAPHS) { gstart[NGRAPHS] = N; return; }
  int lo = 0, hi = N;
  while (lo < hi) {
    int mid = (lo + hi) >> 1;
    if (batch[mid] < g) lo = mid + 1; else hi = mid;
  }
  gstart[g] = lo;
}

// ---------- segmented pooling: grid = NGRAPHS*8, one atomic pair per (block,channel) ----------
__global__ __launch_bounds__(256) void pool_seg_k(const float* __restrict__ x,
                                                  const int* __restrict__ gstart,
                                                  unsigned* __restrict__ gmax,
                                                  float* __restrict__ gsum) {
  int g = blockIdx.x >> 3, s = blockIdx.x & 7;
  int lb = gstart[g], ub = gstart[g + 1];
  long len = ub - lb;
  int i0 = lb + (int)((len * s) >> 3);
  int i1 = lb + (int)((len * (s + 1)) >> 3);
  int c = threadIdx.x & 127, h = threadIdx.x >> 7;
  float m = 0.f, sm = 0.f;
  for (int i = i0 + h; i < i1; i += 2) {
    float v = x[(size_t)i * 128 + c];
    m = fmaxf(m, v);
    sm += v;
  }
  if (i1 > i0) {
    atomicMax(&gmax[g * 128 + c], __float_as_uint(m));
    atomicAdd(&gsum[g * 128 + c], sm);
  }
}

// ---------- head FC1 (fused g0 assembly: max || mean) ----------
__global__ __launch_bounds__(256) void fc1_k(const unsigned* __restrict__ gmax,
                                             const float* __restrict__ gsum,
                                             const int* __restrict__ gstart,
                                             const float* __restrict__ W,
                                             const float* __restrict__ b,
                                             float* __restrict__ Y) {
  __shared__ float xs[256];
  int g = blockIdx.x, c = threadIdx.x;
  float xv;
  if (c < 128) xv = __uint_as_float(gmax[g * 128 + c]);
  else {
    float cnt = (float)(gstart[g + 1] - gstart[g]);
    xv = gsum[g * 128 + (c - 128)] / fmaxf(cnt, 1.f);
  }
  xs[c] = xv;
  __syncthreads();
  float acc = b[c];
  for (int k = 0; k < 256; k++) acc = fmaf(xs[k], W[(size_t)k * 256 + c], acc);
  Y[g * 256 + c] = fmaxf(acc, 0.f);
}

// ---------- head FC2 (relu) ----------
__global__ __launch_bounds__(256) void fc_k(const float* __restrict__ X,
                                            const float* __restrict__ W,
                                            const float* __restrict__ b,
                                            float* __restrict__ Y, int K, int N) {
  __shared__ float xs[256];
  int g = blockIdx.x, c = threadIdx.x;
  for (int k = c; k < K; k += blockDim.x) xs[k] = X[g * K + k];
  __syncthreads();
  float acc = b[c];
  for (int k = 0; k < K; k++) acc = fmaf(xs[k], W[(size_t)k * N + c], acc);
  Y[g * N + c] = fmaxf(acc, 0.f);
}

// ---------- launch ----------
extern "C" void kernel_launch(void* const* d_in, const int* in_sizes, int n_in,
                              void* d_out, int out_size, void* d_ws, size_t ws_size,
                              hipStream_t stream) {
  const float* nodes = (const float*)d_in[0];
  const int* cats = (const int*)d_in[1];
  const int* eidx = (const int*)d_in[2];
  const int* batch = (const int*)d_in[3];
  const float* emb = (const float*)d_in[4];
  const float* W1 = (const float*)d_in[5];
  const float* b1 = (const float*)d_in[6];
  const float* W2 = (const float*)d_in[7];
  const float* b2 = (const float*)d_in[8];
  const float* W3 = (const float*)d_in[9];
  const float* b3 = (const float*)d_in[10];
  const float* We1 = (const float*)d_in[11];
  const float* be1 = (const float*)d_in[12];
  const float* We2 = (const float*)d_in[13];
  const float* be2 = (const float*)d_in[14];
  const float* Wf1 = (const float*)d_in[15];
  const float* bf1 = (const float*)d_in[16];
  const float* Wf2 = (const float*)d_in[17];
  const float* bf2 = (const float*)d_in[18];
  float* out = (float*)d_out;

  const int N = in_sizes[0] / FEAT;
  const int E = in_sizes[2] / 2;
  const int Npad = ((N + 127) / 128) * 128;
  const int* src = eidx;
  const int* dst = eidx + E;

  char* w = (char*)d_ws;
  auto alloc = [&](size_t bytes) -> void* {
    void* p = (void*)w;
    w += (bytes + 255) & ~(size_t)255;
    return p;
  };
  unsigned* xh = (unsigned*)alloc((size_t)Npad * 32 * 4);   // [Npad x 32] u32 (64ch split)
  unsigned* xl = (unsigned*)alloc((size_t)Npad * 32 * 4);
  unsigned* aggh = (unsigned*)alloc((size_t)Npad * 32 * 4); // layer-1 agg output (split)
  unsigned* aggl = (unsigned*)alloc((size_t)Npad * 32 * 4);
  unsigned* ahb = (unsigned*)alloc((size_t)Npad * 64 * 4);  // [Npad x 64] u32 (128ch split)
  unsigned* alb = (unsigned*)alloc((size_t)Npad * 64 * 4);
  float* bufF = (float*)alloc((size_t)Npad * 128 * 4);      // gemm out / U
  float* bufV = (float*)alloc((size_t)Npad * 128 * 4);
  unsigned* agg = (unsigned*)alloc((size_t)N * 128 * 4);
  int* indeg = (int*)alloc((size_t)N * 4);
  int* rowst = (int*)alloc((size_t)(N + 1) * 4);
  int* cursor = (int*)alloc((size_t)N * 4);
  int* exclb = (int*)alloc((size_t)N * 4);
  int* bsum = (int*)alloc(128 * 4);
  float* dinv = (float*)alloc((size_t)N * 4);
  int* csr_src = (int*)alloc((size_t)E * 4);
  int* csr_dst = (int*)alloc((size_t)E * 4);
  float* csr_norm = (float*)alloc((size_t)E * 4);
  unsigned short* W1p = (unsigned short*)alloc(2 * 64 * 128 * 2);
  unsigned short* W2p = (unsigned short*)alloc(2 * 128 * 128 * 2);
  unsigned short* W3p = (unsigned short*)alloc(2 * 128 * 128 * 2);
  unsigned short* Wdp = (unsigned short*)alloc(2 * 128 * 128 * 2);
  unsigned short* Wvp = (unsigned short*)alloc(2 * 128 * 128 * 2);
  unsigned short* We2p = (unsigned short*)alloc(2 * 128 * 128 * 2);
  float* g1buf = (float*)alloc(NGRAPHS * 256 * 4);
  unsigned* gmax = (unsigned*)alloc(NGRAPHS * 128 * 4);
  float* gsum = (float*)alloc(NGRAPHS * 128 * 4);
  int* gstart = (int*)alloc((NGRAPHS + 1) * 4);
  if ((size_t)(w - (char*)d_ws) > ws_size) return;

  hipMemsetAsync(indeg, 0, (size_t)N * 4, stream);
  hipMemsetAsync(agg, 0, (size_t)N * 128 * 4, stream);
  hipMemsetAsync(gmax, 0, NGRAPHS * 128 * 4, stream);
  hipMemsetAsync(gsum, 0, NGRAPHS * 128 * 4, stream);

  const int TB = 256;
  int gE = (E + TB - 1) / TB;
  int nb = (N + 1023) / 1024;

  hist_k<<<gE, TB, 0, stream>>>(dst, indeg, E);
  scanA_k<<<nb, 1024, 0, stream>>>(indeg, exclb, bsum, dinv, N);
  scanB_k<<<1, 64, 0, stream>>>(bsum, nb);
  scanC_k<<<nb, 1024, 0, stream>>>(exclb, bsum, rowst, cursor, N, nb);
  fill_k<<<gE, TB, 0, stream>>>(src, dst, dinv, cursor, csr_src, csr_dst, csr_norm, E);
  gbound_k<<<1, 128, 0, stream>>>(batch, gstart, N);

  xcat_split_k<<<(N * 32 + TB - 1) / TB, TB, 0, stream>>>(nodes, cats, emb, xh, xl, N);
  pack_all_k<<<352, TB, 0, stream>>>(W1, W2, W3, We1, We2, W1p, W2p, W3p, Wdp, Wvp, We2p);

  const int gemmGrid = Npad / 128;
  const int waveGrid = (N * 64 + TB - 1) / TB;

  // layer 1: agg BEFORE gemm (agg(X)@W1 == agg(X@W1); 256 B/row gather instead of 512)
  gcn_aggpre_k<<<waveGrid, TB, 0, stream>>>(xh, xl, csr_src, csr_norm, rowst, dinv, aggh, aggl, N);
  gemm_mfma<<<gemmGrid, TB, 0, stream>>>((unsigned short*)aggh, (unsigned short*)aggl, W1p, bufF, N, 64);
  brs_k<<<(N * 64 + TB - 1) / TB, TB, 0, stream>>>(bufF, b1, ahb, alb, N);
  // layers 2,3: gemm then agg
  gemm_mfma<<<gemmGrid, TB, 0, stream>>>((unsigned short*)ahb, (unsigned short*)alb, W2p, bufF, N, 128);
  gcn_agg_split_k<<<waveGrid, TB, 0, stream>>>(bufF, csr_src, csr_norm, rowst, dinv, b2, ahb, alb, N);
  gemm_mfma<<<gemmGrid, TB, 0, stream>>>((unsigned short*)ahb, (unsigned short*)alb, W3p, bufF, N, 128);
  gcn_agg_split_k<<<waveGrid, TB, 0, stream>>>(bufF, csr_src, csr_norm, rowst, dinv, b3, ahb, alb, N);

  // EdgeConv precompute: U = x3 @ (We1_top - We1_bot) + be1, V = x3 @ We1_bot (fused)
  gemm_dual_mfma<<<gemmGrid, TB, 0, stream>>>((unsigned short*)ahb, (unsigned short*)alb,
                                              Wdp, Wvp, be1, bufF, bufV, N);

  const int ntiles = (E + 127) / 128;
  edgeconv_mfma<<<2048, TB, 0, stream>>>(bufF, bufV, csr_src, csr_dst, We2p, be2, agg, E, ntiles);

  pool_seg_k<<<NGRAPHS * 8, TB, 0, stream>>>((const float*)agg, gstart, gmax, gsum);
  fc1_k<<<NGRAPHS, 256, 0, stream>>>(gmax, gsum, gstart, Wf1, bf1, g1buf);
  fc_k<<<NGRAPHS, 256, 0, stream>>>(g1buf, Wf2, bf2, out, 256, 256);
}

// Round 11
// 594.516 us; speedup vs baseline: 1.5032x; 1.1148x over previous
//
#include <hip/hip_runtime.h>

#define FEAT 32
#define EMB 32
#define HID 128
#define NGRAPHS 64

typedef short short8 __attribute__((ext_vector_type(8)));
typedef float f32x4 __attribute__((ext_vector_type(4)));

union B8 { uint4 q; unsigned u[4]; short8 v; };

// round-to-nearest-even bf16, returned as f32 bits with low16 zeroed (weight-pack path)
__device__ __forceinline__ unsigned bf16_rne_bits(float f) {
  unsigned u = __float_as_uint(f);
  unsigned r = u + 0x7FFFu + ((u >> 16) & 1u);
  return r & 0xFFFF0000u;
}
// split a,b (f32) into packed bf16 hi-pair and lo-pair via v_cvt_pk_bf16_f32.
// lo = a - hi is EXACT in f32 for any bf16 hi (Dekker), so hi+lo represents a
// to 2^-17 regardless of cvt rounding mode.
__device__ __forceinline__ void split2(float a, float b, unsigned& hp, unsigned& lp) {
  unsigned h;
  asm("v_cvt_pk_bf16_f32 %0, %1, %2" : "=v"(h) : "v"(a), "v"(b));
  float ra = a - __uint_as_float(h << 16);
  float rb = b - __uint_as_float(h & 0xFFFF0000u);
  unsigned l;
  asm("v_cvt_pk_bf16_f32 %0, %1, %2" : "=v"(l) : "v"(ra), "v"(rb));
  hp = h;
  lp = l;
}

// ---------- CSR build ----------
__global__ void hist_k(const int* __restrict__ dst, int* __restrict__ indeg, int E) {
  int e = blockIdx.x * blockDim.x + threadIdx.x;
  if (e < E) atomicAdd(&indeg[dst[e]], 1);
}

// ---------- parallel 3-phase exclusive scan of indeg (also computes dinv) ----------
__global__ __launch_bounds__(1024) void scanA_k(const int* __restrict__ indeg,
                                                int* __restrict__ excl,
                                                int* __restrict__ bsum,
                                                float* __restrict__ dinv, int N) {
  __shared__ int wsum[16];
  int i = blockIdx.x * 1024 + threadIdx.x;
  const int lane = threadIdx.x & 63;
  const int wid = threadIdx.x >> 6;
  int val = (i < N) ? indeg[i] : 0;
  if (i < N) dinv[i] = rsqrtf((float)val + 1.0f);  // +1 self loop
  int x = val;
#pragma unroll
  for (int off = 1; off < 64; off <<= 1) {
    int y = __shfl_up(x, off, 64);
    if (lane >= off) x += y;
  }
  if (lane == 63) wsum[wid] = x;
  __syncthreads();
  if (wid == 0) {
    int s = (lane < 16) ? wsum[lane] : 0;
#pragma unroll
    for (int off = 1; off < 16; off <<= 1) {
      int y = __shfl_up(s, off, 64);
      if (lane >= off) s += y;
    }
    if (lane < 16) wsum[lane] = s;
  }
  __syncthreads();
  int ex = x - val + ((wid > 0) ? wsum[wid - 1] : 0);
  if (i < N) excl[i] = ex;
  if (threadIdx.x == 0) bsum[blockIdx.x] = wsum[15];
}

// wave 0: block-sum scan (nb <= 64). wave 1: graph boundaries (batch sorted).
__global__ void scanB_k(int* __restrict__ bsum, int nb, const int* __restrict__ batch,
                        int* __restrict__ gstart, int N) {
  int t = threadIdx.x;
  if (t < 64) {
    int lane = t;
    int v = (lane < nb) ? bsum[lane] : 0;
    int x = v;
#pragma unroll
    for (int off = 1; off < 64; off <<= 1) {
      int y = __shfl_up(x, off, 64);
      if (lane >= off) x += y;
    }
    if (lane < nb) bsum[lane] = x - v;
    if (lane == nb - 1) bsum[nb] = x;  // grand total
  } else {
    int g = t - 64;  // 0..63
    int lo = 0, hi = N;
    while (lo < hi) {
      int mid = (lo + hi) >> 1;
      if (batch[mid] < g) lo = mid + 1; else hi = mid;
    }
    gstart[g] = lo;
    if (g == NGRAPHS - 1) gstart[NGRAPHS] = N;
  }
}

__global__ __launch_bounds__(1024) void scanC_k(const int* __restrict__ excl,
                                                const int* __restrict__ bsum,
                                                int* __restrict__ row_start,
                                                int* __restrict__ cursor, int N, int nb) {
  int i = blockIdx.x * 1024 + threadIdx.x;
  if (i < N) {
    int v = excl[i] + bsum[blockIdx.x];
    row_start[i] = v;
    cursor[i] = v;
  }
  if (i == 0) row_start[N] = bsum[nb];
}

__global__ void fill_k(const int* __restrict__ src, const int* __restrict__ dst,
                       const float* __restrict__ dinv, int* __restrict__ cursor,
                       int* __restrict__ csr_src, int* __restrict__ csr_dst,
                       float* __restrict__ csr_norm, int E) {
  int e = blockIdx.x * blockDim.x + threadIdx.x;
  if (e >= E) return;
  int d = dst[e], s = src[e];
  int p = atomicAdd(&cursor[d], 1);
  csr_src[p] = s;
  csr_dst[p] = d;
  csr_norm[p] = dinv[s] * dinv[d];
}

// ---------- weight packs + xcat split, one launch ----------
// pack layout: out[((kt*4+ks)*128 + c)*8 + j] = bf16(W[kt*32+ks*8+j][c]); lo at +K*128
__global__ void prep_k(const float* __restrict__ W1, const float* __restrict__ W2,
                       const float* __restrict__ W3, const float* __restrict__ We1,
                       const float* __restrict__ We2,
                       unsigned short* __restrict__ W1p, unsigned short* __restrict__ W2p,
                       unsigned short* __restrict__ W3p, unsigned short* __restrict__ Wdp,
                       unsigned short* __restrict__ Wvp, unsigned short* __restrict__ We2p,
                       const float* __restrict__ nodes, const int* __restrict__ cats,
                       const float* __restrict__ emb, unsigned* __restrict__ xh,
                       unsigned* __restrict__ xl, int N) {
  int b = blockIdx.x;
  if (b >= 352) {  // xcat-split part
    int t = (b - 352) * 256 + threadIdx.x;  // N*32, 2 channels each
    if (t >= N * 32) return;
    int i = t >> 5, p = t & 31;
    float2 v = (p < 16) ? ((const float2*)nodes)[(size_t)i * 16 + p]
                        : ((const float2*)emb)[(size_t)cats[i] * 16 + (p - 16)];
    unsigned hp, lp;
    split2(v.x, v.y, hp, lp);
    xh[(size_t)i * 32 + p] = hp;
    xl[(size_t)i * 32 + p] = lp;
    return;
  }
  // pack part: 32 + 5*64 = 352 blocks
  const float* WA;
  const float* WB = nullptr;
  unsigned short* out;
  int K, t0;
  if (b < 32)       { WA = W1;            out = W1p;  K = 64;  t0 = b; }
  else if (b < 96)  { WA = W2;            out = W2p;  K = 128; t0 = b - 32; }
  else if (b < 160) { WA = W3;            out = W3p;  K = 128; t0 = b - 96; }
  else if (b < 224) { WA = We1; WB = We1 + 16384; out = Wdp; K = 128; t0 = b - 160; }
  else if (b < 288) { WA = We1 + 16384;   out = Wvp;  K = 128; t0 = b - 224; }
  else              { WA = We2;           out = We2p; K = 128; t0 = b - 288; }
  int t = t0 * 256 + threadIdx.x;
  if (t >= K * 128) return;
  int k = t >> 7, c = t & 127;
  float v = WA[k * 128 + c];
  if (WB) v -= WB[k * 128 + c];
  unsigned hb = bf16_rne_bits(v);
  float lo = v - __uint_as_float(hb);
  unsigned lb = bf16_rne_bits(lo);
  int kt = k >> 5, ks = (k >> 3) & 3, j = k & 7;
  int idx = ((kt * 4 + ks) * 128 + c) * 8 + j;
  out[idx] = (unsigned short)(hb >> 16);
  out[K * 128 + idx] = (unsigned short)(lb >> 16);
}

// ---------- layer-1 aggregation BEFORE GEMM: gathers 64-ch split rows (256 B/row) ----------
__global__ __launch_bounds__(256) void gcn_aggpre_k(
    const unsigned* __restrict__ xh, const unsigned* __restrict__ xl,
    const int* __restrict__ csr_src, const float* __restrict__ csr_norm,
    const int* __restrict__ row_start, const float* __restrict__ dinv,
    unsigned* __restrict__ out_hi, unsigned* __restrict__ out_lo, int N) {
  int i = (blockIdx.x * blockDim.x + threadIdx.x) >> 6;
  int lane = threadIdx.x & 63;
  if (i >= N) return;
  const int g = lane >> 5, cp = lane & 31;
  float a0 = 0.f, a1 = 0.f;
  int s0 = row_start[i], s1 = row_start[i + 1];
  if (g == 0) {  // self term
    float di = dinv[i];
    float sn = di * di;
    unsigned uh = xh[(size_t)i * 32 + cp], ul = xl[(size_t)i * 32 + cp];
    float x0 = __uint_as_float(uh << 16) + __uint_as_float(ul << 16);
    float x1 = __uint_as_float(uh & 0xFFFF0000u) + __uint_as_float(ul & 0xFFFF0000u);
    a0 = x0 * sn;
    a1 = x1 * sn;
  }
  for (int p = s0 + g; p < s1; p += 8) {
    int idx[4]; float wt[4];
#pragma unroll
    for (int j = 0; j < 4; ++j) {
      int q = p + 2 * j;
      if (q < s1) { idx[j] = csr_src[q]; wt[j] = csr_norm[q]; }
      else        { idx[j] = 0;          wt[j] = 0.f; }
    }
#pragma unroll
    for (int j = 0; j < 4; ++j) {
      unsigned uh = xh[(size_t)idx[j] * 32 + cp], ul = xl[(size_t)idx[j] * 32 + cp];
      float x0 = __uint_as_float(uh << 16) + __uint_as_float(ul << 16);
      float x1 = __uint_as_float(uh & 0xFFFF0000u) + __uint_as_float(ul & 0xFFFF0000u);
      a0 = fmaf(x0, wt[j], a0);
      a1 = fmaf(x1, wt[j], a1);
    }
  }
  a0 += __shfl_xor(a0, 32);
  a1 += __shfl_xor(a1, 32);
  if (g == 0) {
    unsigned hp, lp;
    split2(a0, a1, hp, lp);
    out_hi[(size_t)i * 32 + cp] = hp;
    out_lo[(size_t)i * 32 + cp] = lp;
  }
}

// ---------- bias + relu + split (layer-1 GEMM epilogue) ----------
__global__ void brs_k(const float* __restrict__ h, const float* __restrict__ bias,
                      unsigned* __restrict__ out_hi, unsigned* __restrict__ out_lo, int N) {
  int t = blockIdx.x * blockDim.x + threadIdx.x;  // N*64 channel pairs
  if (t >= N * 64) return;
  int i = t >> 6, p = t & 63;
  float2 v = ((const float2*)h)[(size_t)i * 64 + p];
  float2 bv = ((const float2*)bias)[p];
  float a0 = fmaxf(v.x + bv.x, 0.f), a1 = fmaxf(v.y + bv.y, 0.f);
  unsigned hp, lp;
  split2(a0, a1, hp, lp);
  out_hi[(size_t)i * 64 + p] = hp;
  out_lo[(size_t)i * 64 + p] = lp;
}

// ---------- split-bf16 MFMA GEMM: C[M x 128] = A @ B ; A row-major K, B packed ----------
__global__ __launch_bounds__(256) void gemm_mfma(const unsigned short* __restrict__ Ah,
                                                 const unsigned short* __restrict__ Al,
                                                 const unsigned short* __restrict__ Bp,
                                                 float* __restrict__ C, int M, int K) {
  __shared__ uint4 Blds[4096];  // 64KB max (K=128); K=64 uses 2048
  const int nq = K * 32;        // uint4 count (hi+lo)
  for (int i = threadIdx.x; i < nq; i += 256) Blds[i] = ((const uint4*)Bp)[i];
  __syncthreads();
  const int w = threadIdx.x >> 6, lane = threadIdx.x & 63;
  const int ks = lane >> 4, fr = lane & 15;
  const int rb0 = blockIdx.x * 128 + w * 32;
  const int loBase = K * 16;  // uint4 offset of lo half
  f32x4 acc[2][8];
#pragma unroll
  for (int m = 0; m < 2; ++m)
#pragma unroll
    for (int ct = 0; ct < 8; ++ct) acc[m][ct] = (f32x4)0.f;

  const int nkt = K >> 5;
  for (int kt = 0; kt < nkt; ++kt) {
    B8 ah[2], al[2];
#pragma unroll
    for (int m = 0; m < 2; ++m) {
      size_t off = (size_t)(rb0 + m * 16 + fr) * K + kt * 32 + ks * 8;
      ah[m].q = *(const uint4*)(Ah + off);
      al[m].q = *(const uint4*)(Al + off);
    }
#pragma unroll
    for (int ct = 0; ct < 8; ++ct) {
      int bidx = (kt * 4 + ks) * 128 + ct * 16 + fr;
      B8 bh, bl;
      bh.q = Blds[bidx];
      bl.q = Blds[bidx + loBase];
#pragma unroll
      for (int m = 0; m < 2; ++m) {
        acc[m][ct] = __builtin_amdgcn_mfma_f32_16x16x32_bf16(ah[m].v, bh.v, acc[m][ct], 0, 0, 0);
        acc[m][ct] = __builtin_amdgcn_mfma_f32_16x16x32_bf16(ah[m].v, bl.v, acc[m][ct], 0, 0, 0);
        acc[m][ct] = __builtin_amdgcn_mfma_f32_16x16x32_bf16(al[m].v, bh.v, acc[m][ct], 0, 0, 0);
      }
    }
  }
#pragma unroll
  for (int m = 0; m < 2; ++m)
#pragma unroll
    for (int ct = 0; ct < 8; ++ct) {
      int col = ct * 16 + fr;
#pragma unroll
      for (int r = 0; r < 4; ++r) {
        int row = rb0 + m * 16 + ks * 4 + r;
        if (row < M) C[(size_t)row * 128 + col] = acc[m][ct][r];
      }
    }
}

// ---------- dual GEMM (K=128): U = A@B1 + bias1, V = A@B2 ; A-frags loaded once ----------
__global__ __launch_bounds__(256) void gemm_dual_mfma(const unsigned short* __restrict__ Ah,
                                                      const unsigned short* __restrict__ Al,
                                                      const unsigned short* __restrict__ Bp1,
                                                      const unsigned short* __restrict__ Bp2,
                                                      const float* __restrict__ bias1,
                                                      float* __restrict__ U,
                                                      float* __restrict__ V, int M) {
  __shared__ uint4 Blds[4096];
  for (int i = threadIdx.x; i < 4096; i += 256) Blds[i] = ((const uint4*)Bp1)[i];
  const int w = threadIdx.x >> 6, lane = threadIdx.x & 63;
  const int ks = lane >> 4, fr = lane & 15;
  const int rb0 = blockIdx.x * 128 + w * 32;
  B8 ah[2][4], al[2][4];
#pragma unroll
  for (int m = 0; m < 2; ++m)
#pragma unroll
    for (int kt = 0; kt < 4; ++kt) {
      size_t off = (size_t)(rb0 + m * 16 + fr) * 128 + kt * 32 + ks * 8;
      ah[m][kt].q = *(const uint4*)(Ah + off);
      al[m][kt].q = *(const uint4*)(Al + off);
    }
  __syncthreads();

  f32x4 acc[2][8];
#pragma unroll
  for (int m = 0; m < 2; ++m)
#pragma unroll
    for (int ct = 0; ct < 8; ++ct) acc[m][ct] = (f32x4)0.f;
#pragma unroll
  for (int kt = 0; kt < 4; ++kt)
#pragma unroll
    for (int ct = 0; ct < 8; ++ct) {
      int bidx = (kt * 4 + ks) * 128 + ct * 16 + fr;
      B8 bh, bl;
      bh.q = Blds[bidx];
      bl.q = Blds[bidx + 2048];
#pragma unroll
      for (int m = 0; m < 2; ++m) {
        acc[m][ct] = __builtin_amdgcn_mfma_f32_16x16x32_bf16(ah[m][kt].v, bh.v, acc[m][ct], 0, 0, 0);
        acc[m][ct] = __builtin_amdgcn_mfma_f32_16x16x32_bf16(ah[m][kt].v, bl.v, acc[m][ct], 0, 0, 0);
        acc[m][ct] = __builtin_amdgcn_mfma_f32_16x16x32_bf16(al[m][kt].v, bh.v, acc[m][ct], 0, 0, 0);
      }
    }
#pragma unroll
  for (int m = 0; m < 2; ++m)
#pragma unroll
    for (int ct = 0; ct < 8; ++ct) {
      int col = ct * 16 + fr;
      float bv = bias1[col];
#pragma unroll
      for (int r = 0; r < 4; ++r) {
        int row = rb0 + m * 16 + ks * 4 + r;
        if (row < M) U[(size_t)row * 128 + col] = acc[m][ct][r] + bv;
      }
    }

  __syncthreads();  // all pass-1 LDS reads done
  for (int i = threadIdx.x; i < 4096; i += 256) Blds[i] = ((const uint4*)Bp2)[i];
  __syncthreads();

#pragma unroll
  for (int m = 0; m < 2; ++m)
#pragma unroll
    for (int ct = 0; ct < 8; ++ct) acc[m][ct] = (f32x4)0.f;
#pragma unroll
  for (int kt = 0; kt < 4; ++kt)
#pragma unroll
    for (int ct = 0; ct < 8; ++ct) {
      int bidx = (kt * 4 + ks) * 128 + ct * 16 + fr;
      B8 bh, bl;
      bh.q = Blds[bidx];
      bl.q = Blds[bidx + 2048];
#pragma unroll
      for (int m = 0; m < 2; ++m) {
        acc[m][ct] = __builtin_amdgcn_mfma_f32_16x16x32_bf16(ah[m][kt].v, bh.v, acc[m][ct], 0, 0, 0);
        acc[m][ct] = __builtin_amdgcn_mfma_f32_16x16x32_bf16(ah[m][kt].v, bl.v, acc[m][ct], 0, 0, 0);
        acc[m][ct] = __builtin_amdgcn_mfma_f32_16x16x32_bf16(al[m][kt].v, bh.v, acc[m][ct], 0, 0, 0);
      }
    }
#pragma unroll
  for (int m = 0; m < 2; ++m)
#pragma unroll
    for (int ct = 0; ct < 8; ++ct) {
      int col = ct * 16 + fr;
#pragma unroll
      for (int r = 0; r < 4; ++r) {
        int row = rb0 + m * 16 + ks * 4 + r;
        if (row < M) V[(size_t)row * 128 + col] = acc[m][ct][r];
      }
    }
}

// ---------- GCN aggregate + relu + split to bf16 hi/lo (layers 2,3) ----------
// wave = 1 node; 4 lane-groups of 16 process neighbors mod-4; 8 ch/lane (2xfloat4).
__global__ __launch_bounds__(256) void gcn_agg_split_k(
    const float* __restrict__ h, const int* __restrict__ csr_src,
    const float* __restrict__ csr_norm, const int* __restrict__ row_start,
    const float* __restrict__ dinv, const float* __restrict__ bias,
    unsigned* __restrict__ out_hi, unsigned* __restrict__ out_lo, int N) {
  int i = (blockIdx.x * blockDim.x + threadIdx.x) >> 6;
  int lane = threadIdx.x & 63;
  if (i >= N) return;
  const int g = lane >> 4, c8 = (lane & 15) * 8;
  float4 a0 = make_float4(0.f, 0.f, 0.f, 0.f);
  float4 a1 = make_float4(0.f, 0.f, 0.f, 0.f);
  int s0 = row_start[i], s1 = row_start[i + 1];
  if (g == 0) {  // self term
    float di = dinv[i];
    float sn = di * di;
    float4 v0 = *(const float4*)&h[(size_t)i * 128 + c8];
    float4 v1 = *(const float4*)&h[(size_t)i * 128 + c8 + 4];
    a0.x = v0.x * sn; a0.y = v0.y * sn; a0.z = v0.z * sn; a0.w = v0.w * sn;
    a1.x = v1.x * sn; a1.y = v1.y * sn; a1.z = v1.z * sn; a1.w = v1.w * sn;
  }
  for (int p = s0 + g; p < s1; p += 16) {
    int idx[4]; float wt[4];
#pragma unroll
    for (int j = 0; j < 4; ++j) {
      int q = p + 4 * j;
      if (q < s1) { idx[j] = csr_src[q]; wt[j] = csr_norm[q]; }
      else        { idx[j] = 0;          wt[j] = 0.f; }
    }
#pragma unroll
    for (int j = 0; j < 4; ++j) {
      const float4* hp = (const float4*)&h[(size_t)idx[j] * 128 + c8];
      float4 h0 = hp[0], h1 = hp[1];
      float wgt = wt[j];
      a0.x = fmaf(h0.x, wgt, a0.x); a0.y = fmaf(h0.y, wgt, a0.y);
      a0.z = fmaf(h0.z, wgt, a0.z); a0.w = fmaf(h0.w, wgt, a0.w);
      a1.x = fmaf(h1.x, wgt, a1.x); a1.y = fmaf(h1.y, wgt, a1.y);
      a1.z = fmaf(h1.z, wgt, a1.z); a1.w = fmaf(h1.w, wgt, a1.w);
    }
  }
  // combine across 4 groups (lanes differing in bits 4,5)
#pragma unroll
  for (int off = 16; off < 64; off <<= 1) {
    a0.x += __shfl_xor(a0.x, off); a0.y += __shfl_xor(a0.y, off);
    a0.z += __shfl_xor(a0.z, off); a0.w += __shfl_xor(a0.w, off);
    a1.x += __shfl_xor(a1.x, off); a1.y += __shfl_xor(a1.y, off);
    a1.z += __shfl_xor(a1.z, off); a1.w += __shfl_xor(a1.w, off);
  }
  if (g == 0) {
    float4 b0 = *(const float4*)&bias[c8];
    float4 b1 = *(const float4*)&bias[c8 + 4];
    float v0 = fmaxf(a0.x + b0.x, 0.f), v1 = fmaxf(a0.y + b0.y, 0.f);
    float v2 = fmaxf(a0.z + b0.z, 0.f), v3 = fmaxf(a0.w + b0.w, 0.f);
    float v4 = fmaxf(a1.x + b1.x, 0.f), v5 = fmaxf(a1.y + b1.y, 0.f);
    float v6 = fmaxf(a1.z + b1.z, 0.f), v7 = fmaxf(a1.w + b1.w, 0.f);
    uint4 hh, ll;
    split2(v0, v1, hh.x, ll.x);
    split2(v2, v3, hh.y, ll.y);
    split2(v4, v5, hh.z, ll.z);
    split2(v6, v7, hh.w, ll.w);
    *(uint4*)&out_hi[(size_t)i * 64 + (lane & 15) * 4] = hh;
    *(uint4*)&out_lo[(size_t)i * 64 + (lane & 15) * 4] = ll;
  }
}

// ---------- EdgeConv: MFMA split-bf16, cross-tile software pipeline, run-length max ----------
// 256 threads / 128-edge tiles, interleaved grid-stride (occupancy sweet spot: 2 blocks/CU,
// VGPR free up to 256 — forcing lower spills, R7). kt=3 slot preloads NEXT tile's kt0 rows.
__global__ __launch_bounds__(256) void edgeconv_mfma(
    const float* __restrict__ U, const float* __restrict__ V,
    const int* __restrict__ csr_src, const int* __restrict__ csr_dst,
    const unsigned short* __restrict__ We2p, const float* __restrict__ be2,
    unsigned* __restrict__ agg, int E, int ntiles) {
  __shared__ uint4 Blds[4096];  // We2 hi (2048) + lo (2048)
  for (int i = threadIdx.x; i < 4096; i += 256) Blds[i] = ((const uint4*)We2p)[i];
  __syncthreads();
  const int w = threadIdx.x >> 6, lane = threadIdx.x & 63;
  const int ks = lane >> 4, fr = lane & 15;
  float b2[8];
#pragma unroll
  for (int ct = 0; ct < 8; ++ct) b2[ct] = be2[ct * 16 + fr];

  auto loadIdx = [&](int t, int (&d)[2], int (&s)[2]) {
    const int eb = t * 128 + w * 32;
#pragma unroll
    for (int m = 0; m < 2; ++m) {
      int el = ((fr >> 2) << 3) + (m << 2) + (fr & 3);
      int e = eb + el;
      int ee = (e < E) ? e : 0;
      d[m] = csr_dst[ee];
      s[m] = csr_src[ee];
    }
  };

  int tile = blockIdx.x;
  int dA[2] = {0, 0}, sA[2] = {0, 0};
  // pipeline state: buf0 holds current tile's kt0 rows on loop entry
  float4 ru[2][2][2], rv[2][2][2];
  if (tile < ntiles) {
    loadIdx(tile, dA, sA);
    const int k0 = ks * 8;
#pragma unroll
    for (int m = 0; m < 2; ++m) {
      const float4* up = (const float4*)&U[(size_t)dA[m] * 128 + k0];
      const float4* vp = (const float4*)&V[(size_t)sA[m] * 128 + k0];
      ru[0][m][0] = up[0]; ru[0][m][1] = up[1];
      rv[0][m][0] = vp[0]; rv[0][m][1] = vp[1];
    }
  }

  for (; tile < ntiles; tile += gridDim.x) {
    const int eb = tile * 128 + w * 32;
    int dN[2] = {0, 0}, sN[2] = {0, 0};
    const int tn = tile + gridDim.x;
    if (tn < ntiles) loadIdx(tn, dN, sN);  // next-tile index prefetch

    f32x4 acc[2][8];
#pragma unroll
    for (int m = 0; m < 2; ++m)
#pragma unroll
      for (int ct = 0; ct < 8; ++ct) acc[m][ct] = (f32x4)0.f;

#pragma unroll
    for (int kt = 0; kt < 4; ++kt) {
      const int cb = kt & 1, nb = cb ^ 1;
      if (kt < 3) {  // issue next kt's loads before compute
        const int k0n = (kt + 1) * 32 + ks * 8;
#pragma unroll
        for (int m = 0; m < 2; ++m) {
          const float4* up = (const float4*)&U[(size_t)dA[m] * 128 + k0n];
          const float4* vp = (const float4*)&V[(size_t)sA[m] * 128 + k0n];
          ru[nb][m][0] = up[0]; ru[nb][m][1] = up[1];
          rv[nb][m][0] = vp[0]; rv[nb][m][1] = vp[1];
        }
      } else {  // kt==3, nb==0: preload NEXT tile's kt0 rows -> hides tile-start latency
        const int k0n = ks * 8;
#pragma unroll
        for (int m = 0; m < 2; ++m) {
          const float4* up = (const float4*)&U[(size_t)dN[m] * 128 + k0n];
          const float4* vp = (const float4*)&V[(size_t)sN[m] * 128 + k0n];
          ru[0][m][0] = up[0]; ru[0][m][1] = up[1];
          rv[0][m][0] = vp[0]; rv[0][m][1] = vp[1];
        }
      }
      B8 ah[2], al[2];
#pragma unroll
      for (int m = 0; m < 2; ++m) {
        float4 u0 = ru[cb][m][0], u1 = ru[cb][m][1];
        float4 v0 = rv[cb][m][0], v1 = rv[cb][m][1];
        float s0 = fmaxf(u0.x + v0.x, 0.f);
        float s1 = fmaxf(u0.y + v0.y, 0.f);
        float s2 = fmaxf(u0.z + v0.z, 0.f);
        float s3 = fmaxf(u0.w + v0.w, 0.f);
        float s4 = fmaxf(u1.x + v1.x, 0.f);
        float s5 = fmaxf(u1.y + v1.y, 0.f);
        float s6 = fmaxf(u1.z + v1.z, 0.f);
        float s7 = fmaxf(u1.w + v1.w, 0.f);
        split2(s0, s1, ah[m].u[0], al[m].u[0]);
        split2(s2, s3, ah[m].u[1], al[m].u[1]);
        split2(s4, s5, ah[m].u[2], al[m].u[2]);
        split2(s6, s7, ah[m].u[3], al[m].u[3]);
      }
      __builtin_amdgcn_s_setprio(1);
#pragma unroll
      for (int ct = 0; ct < 8; ++ct) {
        int bidx = (kt * 4 + ks) * 128 + ct * 16 + fr;
        B8 bh, bl;
        bh.q = Blds[bidx];
        bl.q = Blds[bidx + 2048];
#pragma unroll
        for (int m = 0; m < 2; ++m) {
          acc[m][ct] = __builtin_amdgcn_mfma_f32_16x16x32_bf16(ah[m].v, bh.v, acc[m][ct], 0, 0, 0);
          acc[m][ct] = __builtin_amdgcn_mfma_f32_16x16x32_bf16(ah[m].v, bl.v, acc[m][ct], 0, 0, 0);
          acc[m][ct] = __builtin_amdgcn_mfma_f32_16x16x32_bf16(al[m].v, bh.v, acc[m][ct], 0, 0, 0);
        }
      }
      __builtin_amdgcn_s_setprio(0);
    }
    // epilogue: lane's 8 consecutive edges = (m,r) regs; run-length max, relu-first atomicMax
    const int ebase = eb + ks * 8;
    int prev = -1;
    float runv[8];
#pragma unroll
    for (int j = 0; j < 8; ++j) {
      int e = ebase + j;
      if (e < E) {
        int d = csr_dst[e];
        const int m = j >> 2, r = j & 3;
        if (d != prev) {
          if (prev >= 0) {
#pragma unroll
            for (int ct = 0; ct < 8; ++ct)
              atomicMax(&agg[(size_t)prev * 128 + ct * 16 + fr], __float_as_uint(runv[ct]));
          }
          prev = d;
#pragma unroll
          for (int ct = 0; ct < 8; ++ct) runv[ct] = fmaxf(acc[m][ct][r] + b2[ct], 0.f);
        } else {
#pragma unroll
          for (int ct = 0; ct < 8; ++ct)
            runv[ct] = fmaxf(runv[ct], fmaxf(acc[m][ct][r] + b2[ct], 0.f));
        }
      }
    }
    if (prev >= 0) {
#pragma unroll
      for (int ct = 0; ct < 8; ++ct)
        atomicMax(&agg[(size_t)prev * 128 + ct * 16 + fr], __float_as_uint(runv[ct]));
    }
    dA[0] = dN[0]; dA[1] = dN[1];
    sA[0] = sN[0]; sA[1] = sN[1];
  }
}

// ---------- segmented pooling: grid = NGRAPHS*8, one atomic pair per (block,channel) ----------
__global__ __launch_bounds__(256) void pool_seg_k(const float* __restrict__ x,
                                                  const int* __restrict__ gstart,
                                                  unsigned* __restrict__ gmax,
                                                  float* __restrict__ gsum) {
  int g = blockIdx.x >> 3, s = blockIdx.x & 7;
  int lb = gstart[g], ub = gstart[g + 1];
  long len = ub - lb;
  int i0 = lb + (int)((len * s) >> 3);
  int i1 = lb + (int)((len * (s + 1)) >> 3);
  int c = threadIdx.x & 127, h = threadIdx.x >> 7;
  float m = 0.f, sm = 0.f;
  for (int i = i0 + h; i < i1; i += 2) {
    float v = x[(size_t)i * 128 + c];
    m = fmaxf(m, v);
    sm += v;
  }
  if (i1 > i0) {
    atomicMax(&gmax[g * 128 + c], __float_as_uint(m));
    atomicAdd(&gsum[g * 128 + c], sm);
  }
}

// ---------- fused head: g0 assembly (max || mean) -> FC1 relu -> FC2 relu ----------
__global__ __launch_bounds__(256) void head_k(const unsigned* __restrict__ gmax,
                                              const float* __restrict__ gsum,
                                              const int* __restrict__ gstart,
                                              const float* __restrict__ Wf1,
                                              const float* __restrict__ bf1,
                                              const float* __restrict__ Wf2,
                                              const float* __restrict__ bf2,
                                              float* __restrict__ out) {
  __shared__ float xs[256];
  __shared__ float ys[256];
  int g = blockIdx.x, c = threadIdx.x;
  float xv;
  if (c < 128) xv = __uint_as_float(gmax[g * 128 + c]);
  else {
    float cnt = (float)(gstart[g + 1] - gstart[g]);
    xv = gsum[g * 128 + (c - 128)] / fmaxf(cnt, 1.f);
  }
  xs[c] = xv;
  __syncthreads();
  float acc = bf1[c];
  for (int k = 0; k < 256; k++) acc = fmaf(xs[k], Wf1[(size_t)k * 256 + c], acc);
  ys[c] = fmaxf(acc, 0.f);
  __syncthreads();
  acc = bf2[c];
  for (int k = 0; k < 256; k++) acc = fmaf(ys[k], Wf2[(size_t)k * 256 + c], acc);
  out[g * 256 + c] = fmaxf(acc, 0.f);
}

// ---------- launch ----------
extern "C" void kernel_launch(void* const* d_in, const int* in_sizes, int n_in,
                              void* d_out, int out_size, void* d_ws, size_t ws_size,
                              hipStream_t stream) {
  const float* nodes = (const float*)d_in[0];
  const int* cats = (const int*)d_in[1];
  const int* eidx = (const int*)d_in[2];
  const int* batch = (const int*)d_in[3];
  const float* emb = (const float*)d_in[4];
  const float* W1 = (const float*)d_in[5];
  const float* b1 = (const float*)d_in[6];
  const float* W2 = (const float*)d_in[7];
  const float* b2 = (const float*)d_in[8];
  const float* W3 = (const float*)d_in[9];
  const float* b3 = (const float*)d_in[10];
  const float* We1 = (const float*)d_in[11];
  const float* be1 = (const float*)d_in[12];
  const float* We2 = (const float*)d_in[13];
  const float* be2 = (const float*)d_in[14];
  const float* Wf1 = (const float*)d_in[15];
  const float* bf1 = (const float*)d_in[16];
  const float* Wf2 = (const float*)d_in[17];
  const float* bf2 = (const float*)d_in[18];
  float* out = (float*)d_out;

  const int N = in_sizes[0] / FEAT;
  const int E = in_sizes[2] / 2;
  const int Npad = ((N + 127) / 128) * 128;
  const int* src = eidx;
  const int* dst = eidx + E;

  char* w = (char*)d_ws;
  auto alloc = [&](size_t bytes) -> void* {
    void* p = (void*)w;
    w += (bytes + 255) & ~(size_t)255;
    return p;
  };
  unsigned* xh = (unsigned*)alloc((size_t)Npad * 32 * 4);   // [Npad x 32] u32 (64ch split)
  unsigned* xl = (unsigned*)alloc((size_t)Npad * 32 * 4);
  unsigned* aggh = (unsigned*)alloc((size_t)Npad * 32 * 4); // layer-1 agg output (split)
  unsigned* aggl = (unsigned*)alloc((size_t)Npad * 32 * 4);
  unsigned* ahb = (unsigned*)alloc((size_t)Npad * 64 * 4);  // [Npad x 64] u32 (128ch split)
  unsigned* alb = (unsigned*)alloc((size_t)Npad * 64 * 4);
  float* bufF = (float*)alloc((size_t)Npad * 128 * 4);      // gemm out / U
  float* bufV = (float*)alloc((size_t)Npad * 128 * 4);
  unsigned* agg = (unsigned*)alloc((size_t)N * 128 * 4);
  int* indeg = (int*)alloc((size_t)N * 4);
  int* rowst = (int*)alloc((size_t)(N + 1) * 4);
  int* cursor = (int*)alloc((size_t)N * 4);
  int* exclb = (int*)alloc((size_t)N * 4);
  int* bsum = (int*)alloc(128 * 4);
  float* dinv = (float*)alloc((size_t)N * 4);
  int* csr_src = (int*)alloc((size_t)E * 4);
  int* csr_dst = (int*)alloc((size_t)E * 4);
  float* csr_norm = (float*)alloc((size_t)E * 4);
  unsigned short* W1p = (unsigned short*)alloc(2 * 64 * 128 * 2);
  unsigned short* W2p = (unsigned short*)alloc(2 * 128 * 128 * 2);
  unsigned short* W3p = (unsigned short*)alloc(2 * 128 * 128 * 2);
  unsigned short* Wdp = (unsigned short*)alloc(2 * 128 * 128 * 2);
  unsigned short* Wvp = (unsigned short*)alloc(2 * 128 * 128 * 2);
  unsigned short* We2p = (unsigned short*)alloc(2 * 128 * 128 * 2);
  unsigned* gmax = (unsigned*)alloc(NGRAPHS * 128 * 4);
  float* gsum = (float*)alloc(NGRAPHS * 128 * 4);
  int* gstart = (int*)alloc((NGRAPHS + 1) * 4);
  if ((size_t)(w - (char*)d_ws) > ws_size) return;

  hipMemsetAsync(indeg, 0, (size_t)N * 4, stream);
  hipMemsetAsync(agg, 0, (size_t)N * 128 * 4, stream);
  hipMemsetAsync(gmax, 0, NGRAPHS * 128 * 4, stream);
  hipMemsetAsync(gsum, 0, NGRAPHS * 128 * 4, stream);

  const int TB = 256;
  int gE = (E + TB - 1) / TB;
  int nb = (N + 1023) / 1024;

  hist_k<<<gE, TB, 0, stream>>>(dst, indeg, E);
  scanA_k<<<nb, 1024, 0, stream>>>(indeg, exclb, bsum, dinv, N);
  scanB_k<<<1, 128, 0, stream>>>(bsum, nb, batch, gstart, N);
  scanC_k<<<nb, 1024, 0, stream>>>(exclb, bsum, rowst, cursor, N, nb);
  fill_k<<<gE, TB, 0, stream>>>(src, dst, dinv, cursor, csr_src, csr_dst, csr_norm, E);

  int prepGrid = 352 + (N * 32 + TB - 1) / TB;
  prep_k<<<prepGrid, TB, 0, stream>>>(W1, W2, W3, We1, We2, W1p, W2p, W3p, Wdp, Wvp, We2p,
                                      nodes, cats, emb, xh, xl, N);

  const int gemmGrid = Npad / 128;
  const int waveGrid = (N * 64 + TB - 1) / TB;

  // layer 1: agg BEFORE gemm (agg(X)@W1 == agg(X@W1); 256 B/row gather instead of 512)
  gcn_aggpre_k<<<waveGrid, TB, 0, stream>>>(xh, xl, csr_src, csr_norm, rowst, dinv, aggh, aggl, N);
  gemm_mfma<<<gemmGrid, TB, 0, stream>>>((unsigned short*)aggh, (unsigned short*)aggl, W1p, bufF, N, 64);
  brs_k<<<(N * 64 + TB - 1) / TB, TB, 0, stream>>>(bufF, b1, ahb, alb, N);
  // layers 2,3: gemm then agg
  gemm_mfma<<<gemmGrid, TB, 0, stream>>>((unsigned short*)ahb, (unsigned short*)alb, W2p, bufF, N, 128);
  gcn_agg_split_k<<<waveGrid, TB, 0, stream>>>(bufF, csr_src, csr_norm, rowst, dinv, b2, ahb, alb, N);
  gemm_mfma<<<gemmGrid, TB, 0, stream>>>((unsigned short*)ahb, (unsigned short*)alb, W3p, bufF, N, 128);
  gcn_agg_split_k<<<waveGrid, TB, 0, stream>>>(bufF, csr_src, csr_norm, rowst, dinv, b3, ahb, alb, N);

  // EdgeConv precompute: U = x3 @ (We1_top - We1_bot) + be1, V = x3 @ We1_bot (fused)
  gemm_dual_mfma<<<gemmGrid, TB, 0, stream>>>((unsigned short*)ahb, (unsigned short*)alb,
                                              Wdp, Wvp, be1, bufF, bufV, N);

  const int ntiles = (E + 127) / 128;
  edgeconv_mfma<<<2048, TB, 0, stream>>>(bufF, bufV, csr_src, csr_dst, We2p, be2, agg, E, ntiles);

  pool_seg_k<<<NGRAPHS * 8, TB, 0, stream>>>((const float*)agg, gstart, gmax, gsum);
  head_k<<<NGRAPHS, 256, 0, stream>>>(gmax, gsum, gstart, Wf1, bf1, Wf2, bf2, out);
}